// Round 10
// baseline (1204.356 us; speedup 1.0000x reference)
//
#include <hip/hip_runtime.h>
#include <math.h>

#define N_NODES  100000
#define N_FEAT   128
#define N_HID    64
#define N_CLASS  10
#define N_GRAPHS 1000
#define N_EDGES  1600000
#define NTILES   1563      // pre-role blocks (64 nodes each)
#define BLK_N    128       // gather_mlp tile
#define NT2      782       // ceil(100000/128)
#define HF_GROUPS 8        // concurrent dst ranges
#define HF_RANGE 12500     // 100000/8
#define HF_BLOCKS 2048     // hist-role blocks
#define HF_GSZ   65536     // (2048/8)*256 threads per range group
#define FUSED_BLOCKS (2*NTILES + (HF_BLOCKS - NTILES))   // 3611
#define CSR_STRIDE 64      // fixed bucket per node; P(deg>=64)~1e-20 @ Poisson(16)
#define EMAX_LDS 32        // staged slots per node; P(deg>32)~1e-4 -> global tail
#define APITCH 72          // bf16 row pitch = 144 B (16B-aligned, 2-way banks)

typedef int iv4 __attribute__((ext_vector_type(4)));
typedef __attribute__((ext_vector_type(8))) __bf16 bf16x8;
typedef __attribute__((ext_vector_type(4))) float f32x4;

// ---- bf16 helpers: h stored bf16 (row = 128 B); arithmetic fp32.
__device__ __forceinline__ float bflo(unsigned u) { return __uint_as_float(u << 16); }
__device__ __forceinline__ float bfhi(unsigned u) { return __uint_as_float(u & 0xffff0000u); }
__device__ __forceinline__ unsigned bf_rne(float f) {
    unsigned u = __float_as_uint(f);
    return (u + 0x7fffu + ((u >> 16) & 1u)) >> 16;
}
__device__ __forceinline__ unsigned pack2(float a, float b) {
    return bf_rne(a) | (bf_rne(b) << 16);
}

// ---- fused pre + hist v10: co-resident block roles, even/odd interleaved.
// v6 failed (155us) because pre's 34.8KB LDS + GEMM VGPRs capped the fused
// kernel at ~3 blocks/CU, starving hist's memory parallelism. v10 pre is
// ZERO-LDS / low-VGPR: per wave 16 nodes in registers (xr[32], acc[16]);
// k-loop fully unrolled: 1 coalesced L1-hot W-row load + 16 readlane (SALU)
// + 16 v_fmac (SGPR operand). VALU ~10us total, x stream 51MB ~8us, W from
// L1 ~5us -- all hidden under hist's 77us (VALU 4%, HBM 22%).
// hist body = v3 (best, 76.5us). v4 lesson (705us): never concentrate the
// 1.6M returning atomics onto few cache lines; keep 100K deg addresses.
__global__ __launch_bounds__(256, 6) void pre_hist_kernel(
    const float* __restrict__ x, const float* __restrict__ W,
    const float* __restrict__ b, unsigned short* __restrict__ h16,
    const int* __restrict__ ei, int* __restrict__ deg, int* __restrict__ csr)
{
    const int bi = blockIdx.x;
    const int tid = threadIdx.x;
    int prei = -1, hb = -1;
    if (bi < 2 * NTILES) {
        if ((bi & 1) == 0) prei = bi >> 1;
        else hb = bi >> 1;
    } else {
        hb = NTILES + (bi - 2 * NTILES);
    }

    if (prei >= 0) {
        // ==== pre role: h0 = x @ pre_w + pre_b (bf16), reg-resident ====
        const int lane = tid & 63;
        const int wv = tid >> 6;              // wave 0..3
        const int nb = prei * 64 + wv * 16;   // this wave's 16 nodes
        float xr[32];
        float acc[16];
#pragma unroll
        for (int i = 0; i < 16; ++i) acc[i] = 0.f;
#pragma unroll
        for (int i = 0; i < 16; ++i) {
            const int node = nb + i;
            const bool ok = node < N_NODES;
            xr[2 * i]     = ok ? x[(size_t)node * N_FEAT + lane]      : 0.f;
            xr[2 * i + 1] = ok ? x[(size_t)node * N_FEAT + 64 + lane] : 0.f;
        }
#pragma unroll
        for (int k = 0; k < 128; ++k) {
            const float wk = W[k * N_HID + lane];    // 256B coalesced, L1-hot
#pragma unroll
            for (int i = 0; i < 16; ++i) {
                const float xk = __int_as_float(__builtin_amdgcn_readlane(
                    __float_as_int(xr[2 * i + (k >> 6)]), k & 63));
                acc[i] = fmaf(xk, wk, acc[i]);
            }
        }
        const float bias = b[lane];
#pragma unroll
        for (int i = 0; i < 16; ++i) {
            const int node = nb + i;
            if (node < N_NODES)
                h16[(size_t)node * N_HID + lane] =
                    (unsigned short)bf_rne(acc[i] + bias);
        }
    } else {
        // ==== hist role: fixed-stride CSR fill (v3 body) ====
        const int r   = hb & (HF_GROUPS - 1);
        const int g   = hb >> 3;
        const int lo  = r * HF_RANGE;
        const int hi  = lo + HF_RANGE;
        const int t0  = g * 256 + tid;
        const iv4* dst4 = (const iv4*)(ei + N_EDGES);
        for (int q = t0; q < N_EDGES / 4; q += HF_GSZ) {
            const iv4 d = __builtin_nontemporal_load(dst4 + q);
            const int e0 = q * 4;
            if (d.x >= lo && d.x < hi) {
                int p = atomicAdd(&deg[d.x], 1);
                if (p < CSR_STRIDE)
                    csr[d.x * CSR_STRIDE + p] = __builtin_nontemporal_load(ei + e0);
            }
            if (d.y >= lo && d.y < hi) {
                int p = atomicAdd(&deg[d.y], 1);
                if (p < CSR_STRIDE)
                    csr[d.y * CSR_STRIDE + p] = __builtin_nontemporal_load(ei + e0 + 1);
            }
            if (d.z >= lo && d.z < hi) {
                int p = atomicAdd(&deg[d.z], 1);
                if (p < CSR_STRIDE)
                    csr[d.z * CSR_STRIDE + p] = __builtin_nontemporal_load(ei + e0 + 2);
            }
            if (d.w >= lo && d.w < hi) {
                int p = atomicAdd(&deg[d.w], 1);
                if (p < CSR_STRIDE)
                    csr[d.w * CSR_STRIDE + p] = __builtin_nontemporal_load(ei + e0 + 3);
            }
        }
    }
}

// ---- fused GIN layer v9 (379us best): v5 paired gather + MFMA bf16 MLP.
// MLP: per wave a 16-row block x 4 col-blocks, mfma_f32_16x16x32_bf16, K=64.
// LDS bf16: asb[128][72] (eidx staged in bytes 0..127/row, overwritten after
// that row's reads -- data-dep-safe), wsb[64][72]=W^T. 28KB total.
__global__ __launch_bounds__(512, 6) void gather_mlp_kernel(
    const uint2* __restrict__ hin, uint2* __restrict__ hout,
    const int* __restrict__ csr, const int* __restrict__ deg,
    const float* __restrict__ W1, const float* __restrict__ b1,
    const float* __restrict__ W2, const float* __restrict__ b2)
{
    __shared__ unsigned short asb[BLK_N][APITCH];  // agg/z/h bf16 (+eidx overlap)
    __shared__ unsigned short wsb[N_HID][APITCH];  // W^T bf16 [n][k]
    __shared__ int sdeg[BLK_N];
    const int tid = threadIdx.x;
    const int tx = tid & 15, ty = tid >> 4;   // ty = gather group 0..31
    const int sub = tx;
    const int n0 = blockIdx.x * BLK_N;

    // stage W1^T bf16
#pragma unroll
    for (int t = 0; t < 8; ++t) {
        const int idx = t * 512 + tid;        // 0..4095: k=idx>>6, n=idx&63
        wsb[idx & 63][idx >> 6] = (unsigned short)bf_rne(W1[idx]);
    }
    if (tid < BLK_N) {
        const int node = n0 + tid;
        sdeg[tid] = (node < N_NODES) ? deg[node] : 0;
    }
    // stage edge indices: 32 ints into bytes [0..128) of each asb row
#pragma unroll
    for (int t = 0; t < 2; ++t) {
        const int idx = t * 512 + tid;        // 0..1023 int4 slots
        const int r = idx >> 3, s4 = idx & 7;
        const int node = n0 + r;
        int4 v = make_int4(0, 0, 0, 0);
        if (node < N_NODES)
            v = *(const int4*)(csr + (size_t)node * CSR_STRIDE + s4 * 4);
        *(int4*)((char*)&asb[r][0] + s4 * 16) = v;
    }
    __syncthreads();

    // gather: group ty owns rows ty, ty+32, ty+64, ty+96; pairs (rA, rB=rA+32),
    // 16 row-loads in flight per group.
    for (int pp = 0; pp < 2; ++pp) {
        const int rA = ty + 64 * pp;
        const int rB = rA + 32;
        const int nodeA = n0 + rA;
        const int nodeB = n0 + rB;
        float aAx = 0.f, aAy = 0.f, aAz = 0.f, aAw = 0.f;
        float bAx = 0.f, bAy = 0.f, bAz = 0.f, bAw = 0.f;
        float aBx = 0.f, aBy = 0.f, aBz = 0.f, aBw = 0.f;
        float bBx = 0.f, bBy = 0.f, bBz = 0.f, bBw = 0.f;
        int nA = 0, nB = 0;
        if (nodeA < N_NODES) {
            nA = sdeg[rA]; nA = nA > CSR_STRIDE ? CSR_STRIDE : nA;
            const uint2 s = hin[(size_t)nodeA * 16 + sub];   // self term
            aAx = bflo(s.x); aAy = bfhi(s.x); aAz = bflo(s.y); aAw = bfhi(s.y);
        }
        if (nodeB < N_NODES) {
            nB = sdeg[rB]; nB = nB > CSR_STRIDE ? CSR_STRIDE : nB;
            const uint2 s = hin[(size_t)nodeB * 16 + sub];   // self term
            aBx = bflo(s.x); aBy = bfhi(s.x); aBz = bflo(s.y); aBw = bfhi(s.y);
        }
        const int nnA = nA > EMAX_LDS ? EMAX_LDS : nA;
        const int nnB = nB > EMAX_LDS ? EMAX_LDS : nB;
        const int* epA = (const int*)&asb[rA][0];
        const int* epB = (const int*)&asb[rB][0];
        const int mx = nnA > nnB ? nnA : nnB;
        for (int eb = 0; eb < mx; eb += 8) {
            uint2 rvA[8], rvB[8];
            const bool doA = eb < nnA;
            const bool doB = eb < nnB;
            if (doA) {
#pragma unroll
                for (int u = 0; u < 8; ++u) {
                    const int idx = eb + u;
                    const int cl = idx < nnA ? idx : nnA - 1;  // clamp: slots>=deg poison
                    rvA[u] = hin[(size_t)epA[cl] * 16 + sub];
                }
            }
            if (doB) {
#pragma unroll
                for (int u = 0; u < 8; ++u) {
                    const int idx = eb + u;
                    const int cl = idx < nnB ? idx : nnB - 1;
                    rvB[u] = hin[(size_t)epB[cl] * 16 + sub];
                }
            }
            if (doA) {
#pragma unroll
                for (int u = 0; u < 8; u += 2) {
                    if (eb + u < nnA) {
                        aAx += bflo(rvA[u].x); aAy += bfhi(rvA[u].x);
                        aAz += bflo(rvA[u].y); aAw += bfhi(rvA[u].y);
                    }
                    if (eb + u + 1 < nnA) {
                        bAx += bflo(rvA[u + 1].x); bAy += bfhi(rvA[u + 1].x);
                        bAz += bflo(rvA[u + 1].y); bAw += bfhi(rvA[u + 1].y);
                    }
                }
            }
            if (doB) {
#pragma unroll
                for (int u = 0; u < 8; u += 2) {
                    if (eb + u < nnB) {
                        aBx += bflo(rvB[u].x); aBy += bfhi(rvB[u].x);
                        aBz += bflo(rvB[u].y); aBw += bfhi(rvB[u].y);
                    }
                    if (eb + u + 1 < nnB) {
                        bBx += bflo(rvB[u + 1].x); bBy += bfhi(rvB[u + 1].x);
                        bBz += bflo(rvB[u + 1].y); bBw += bfhi(rvB[u + 1].y);
                    }
                }
            }
        }
        for (int t = EMAX_LDS; t < nA; ++t) { // rare tail (P~1e-4)
            const int s0 = csr[(size_t)nodeA * CSR_STRIDE + t];
            const uint2 a = hin[(size_t)s0 * 16 + sub];
            aAx += bflo(a.x); aAy += bfhi(a.x);
            aAz += bflo(a.y); aAw += bfhi(a.y);
        }
        for (int t = EMAX_LDS; t < nB; ++t) {
            const int s0 = csr[(size_t)nodeB * CSR_STRIDE + t];
            const uint2 a = hin[(size_t)s0 * 16 + sub];
            aBx += bflo(a.x); aBy += bfhi(a.x);
            aBz += bflo(a.y); aBw += bfhi(a.y);
        }
        // write agg rows bf16 (overwrites this row's eidx -- reads done)
        *(uint2*)((char*)&asb[rA][0] + sub * 8) = make_uint2(
            pack2(aAx + bAx, aAy + bAy), pack2(aAz + bAz, aAw + bAw));
        *(uint2*)((char*)&asb[rB][0] + sub * 8) = make_uint2(
            pack2(aBx + bBx, aBy + bBy), pack2(aBz + bBz, aBw + bBw));
    }
    __syncthreads();

    // ---- MFMA MLP ----
    const int wave = tid >> 6;            // row-block 0..7
    const int lane = tid & 63;
    const int lr = lane & 15;
    const int lg = lane >> 4;
    const f32x4 vzero = {0.f, 0.f, 0.f, 0.f};

    // GEMM1: z = relu(agg @ W1 + b1)
    f32x4 acc[4] = {vzero, vzero, vzero, vzero};
    {
        const char* ar = (const char*)&asb[wave * 16 + lr][0] + lg * 16;
        const bf16x8 a0 = *(const bf16x8*)ar;
        const bf16x8 a1 = *(const bf16x8*)(ar + 64);
#pragma unroll
        for (int cb = 0; cb < 4; ++cb) {
            const char* br = (const char*)&wsb[cb * 16 + lr][0] + lg * 16;
            const bf16x8 w0 = *(const bf16x8*)br;
            const bf16x8 w1 = *(const bf16x8*)(br + 64);
            acc[cb] = __builtin_amdgcn_mfma_f32_16x16x32_bf16(a0, w0, acc[cb], 0, 0, 0);
            acc[cb] = __builtin_amdgcn_mfma_f32_16x16x32_bf16(a1, w1, acc[cb], 0, 0, 0);
        }
    }
#pragma unroll
    for (int cb = 0; cb < 4; ++cb) {
        const float bias = b1[cb * 16 + lr];
#pragma unroll
        for (int rg = 0; rg < 4; ++rg) {
            const float v = fmaxf(acc[cb][rg] + bias, 0.f);
            asb[wave * 16 + lg * 4 + rg][cb * 16 + lr] = (unsigned short)bf_rne(v);
        }
    }
    __syncthreads();                       // all W1 B-frag reads done
#pragma unroll
    for (int t = 0; t < 8; ++t) {
        const int idx = t * 512 + tid;
        wsb[idx & 63][idx >> 6] = (unsigned short)bf_rne(W2[idx]);
    }
    __syncthreads();

    // GEMM2: h = relu(z @ W2 + b2)
#pragma unroll
    for (int cb = 0; cb < 4; ++cb) acc[cb] = vzero;
    {
        const char* ar = (const char*)&asb[wave * 16 + lr][0] + lg * 16;
        const bf16x8 a0 = *(const bf16x8*)ar;
        const bf16x8 a1 = *(const bf16x8*)(ar + 64);
#pragma unroll
        for (int cb = 0; cb < 4; ++cb) {
            const char* br = (const char*)&wsb[cb * 16 + lr][0] + lg * 16;
            const bf16x8 w0 = *(const bf16x8*)br;
            const bf16x8 w1 = *(const bf16x8*)(br + 64);
            acc[cb] = __builtin_amdgcn_mfma_f32_16x16x32_bf16(a0, w0, acc[cb], 0, 0, 0);
            acc[cb] = __builtin_amdgcn_mfma_f32_16x16x32_bf16(a1, w1, acc[cb], 0, 0, 0);
        }
    }
#pragma unroll
    for (int cb = 0; cb < 4; ++cb) {
        const float bias = b2[cb * 16 + lr];
#pragma unroll
        for (int rg = 0; rg < 4; ++rg) {
            const float v = fmaxf(acc[cb][rg] + bias, 0.f);
            asb[wave * 16 + lg * 4 + rg][cb * 16 + lr] = (unsigned short)bf_rne(v);
        }
    }
    __syncthreads();

    // coalesced copy-out
#pragma unroll
    for (int t = 0; t < 4; ++t) {
        const int idx = t * 512 + tid;        // 0..2047
        const int m = idx >> 4, kv = idx & 15;
        if (n0 + m < N_NODES)
            hout[(size_t)(n0 + m) * 16 + kv] =
                *(const uint2*)((const char*)&asb[m][0] + kv * 8);
    }
}

// ---- fused pool+head: block per graph; wave 0 finishes post/ro/log_softmax
// in-register from the pooled row. h is bf16. ----
__global__ __launch_bounds__(256) void pool_head_kernel(
    const unsigned short* __restrict__ h, const int* __restrict__ batch,
    const float* __restrict__ Wp, const float* __restrict__ bp,
    const float* __restrict__ Wr, const float* __restrict__ br,
    float* __restrict__ out)
{
    const int graph = blockIdx.x;
    int l = 0, r = N_NODES;
    while (l < r) { int m = (l + r) >> 1; if (batch[m] < graph) l = m + 1; else r = m; }
    const int lo = l;
    r = N_NODES;
    while (l < r) { int m = (l + r) >> 1; if (batch[m] < graph + 1) l = m + 1; else r = m; }
    const int hi = l;

    const int lane = threadIdx.x & 63;
    const int wave = threadIdx.x >> 6;
    float acc = 0.0f;
    for (int i = lo + wave; i < hi; i += 4)
        acc += __uint_as_float(((unsigned)h[(size_t)i * N_HID + lane]) << 16);
    __shared__ float sacc[4][N_HID];
    sacc[wave][lane] = acc;
    __syncthreads();
    if (wave != 0) return;

    const float gv = sacc[0][lane] + sacc[1][lane] + sacc[2][lane] + sacc[3][lane];
    float acc2 = bp[lane];
#pragma unroll
    for (int k = 0; k < N_HID; ++k) {
        const float gk = __int_as_float(
            __builtin_amdgcn_readlane(__float_as_int(gv), k));
        acc2 = fmaf(gk, Wp[k * N_HID + lane], acc2);
    }
    const float y = fmaxf(acc2, 0.f);

    float logit = (lane < N_CLASS) ? br[lane] : 0.f;
#pragma unroll
    for (int k = 0; k < N_HID; ++k) {
        const float yk = __int_as_float(
            __builtin_amdgcn_readlane(__float_as_int(y), k));
        if (lane < N_CLASS)
            logit = fmaf(yk, Wr[k * N_CLASS + lane], logit);
    }

    __shared__ float slog[N_CLASS];
    if (lane < N_CLASS) slog[lane] = logit;
    if (lane < N_CLASS) {
        float m = -INFINITY;
#pragma unroll
        for (int c = 0; c < N_CLASS; ++c) m = fmaxf(m, slog[c]);
        float sum = 0.0f;
#pragma unroll
        for (int c = 0; c < N_CLASS; ++c) sum += expf(slog[c] - m);
        out[(size_t)graph * N_CLASS + lane] = logit - m - logf(sum);
    }
}

extern "C" void kernel_launch(void* const* d_in, const int* in_sizes, int n_in,
                              void* d_out, int out_size, void* d_ws, size_t ws_size,
                              hipStream_t stream)
{
    const float* x       = (const float*)d_in[0];
    const int*   ei      = (const int*)d_in[1];   // [2, E]: row0=src, row1=dst
    const int*   batch   = (const int*)d_in[2];
    const float* pre_w   = (const float*)d_in[3];
    const float* pre_b   = (const float*)d_in[4];
    const float* conv_w1 = (const float*)d_in[5];
    const float* conv_b1 = (const float*)d_in[6];
    const float* conv_w2 = (const float*)d_in[7];
    const float* conv_b2 = (const float*)d_in[8];
    const float* post_w  = (const float*)d_in[9];
    const float* post_b  = (const float*)d_in[10];
    const float* ro_w    = (const float*)d_in[11];
    const float* ro_b    = (const float*)d_in[12];
    float* out = (float*)d_out;

    // workspace layout (~51.6 MB)
    uint2* h0   = (uint2*)d_ws;                       // 12.8 MB (bf16 h)
    uint2* h1   = h0 + (size_t)N_NODES * 16;          // 12.8 MB
    int*   deg  = (int*)(h1 + (size_t)N_NODES * 16);  // 400 KB
    int*   csr  = deg + N_NODES;                      // 25.6 MB fixed-stride

    (void)hipMemsetAsync(deg, 0, N_NODES * sizeof(int), stream);

    // fused pre + hist (zero-LDS pre role; hist residency preserved)
    pre_hist_kernel<<<FUSED_BLOCKS, 256, 0, stream>>>(
        x, pre_w, pre_b, (unsigned short*)h0, ei, deg, csr);

    // 3 fused GIN layers, h ping-pong h0 -> h1 -> h0 -> h1
    gather_mlp_kernel<<<NT2, 512, 0, stream>>>(
        h0, h1, csr, deg,
        conv_w1, conv_b1, conv_w2, conv_b2);
    gather_mlp_kernel<<<NT2, 512, 0, stream>>>(
        h1, h0, csr, deg,
        conv_w1 + N_HID * N_HID, conv_b1 + N_HID,
        conv_w2 + N_HID * N_HID, conv_b2 + N_HID);
    gather_mlp_kernel<<<NT2, 512, 0, stream>>>(
        h0, h1, csr, deg,
        conv_w1 + 2 * N_HID * N_HID, conv_b1 + 2 * N_HID,
        conv_w2 + 2 * N_HID * N_HID, conv_b2 + 2 * N_HID);

    pool_head_kernel<<<N_GRAPHS, 256, 0, stream>>>(
        (const unsigned short*)h1, batch, post_w, post_b, ro_w, ro_b, out);
}

// Round 11
// 414.085 us; speedup vs baseline: 2.9085x; 2.9085x over previous
//
#include <hip/hip_runtime.h>
#include <math.h>

#define N_NODES  100000
#define N_FEAT   128
#define N_HID    64
#define N_CLASS  10
#define N_GRAPHS 1000
#define N_EDGES  1600000
#define NTILES   1563      // pre-role blocks (64 nodes each)
#define BLK_N    128       // gather_mlp tile
#define NT2      782       // ceil(100000/128)
#define HF_GROUPS 8        // concurrent dst ranges
#define HF_RANGE 12500     // 100000/8
#define HF_BLOCKS 2048     // hist-role blocks
#define HF_GSZ   65536     // (2048/8)*256 threads per range group
#define FUSED_BLOCKS (2*NTILES + (HF_BLOCKS - NTILES))   // 3611
#define CSR_STRIDE 64      // fixed bucket per node; P(deg>=64)~1e-20 @ Poisson(16)
#define EMAX_LDS 32        // staged slots per node; P(deg>32)~1e-4 -> global tail
#define APITCH 72          // bf16 row pitch = 144 B (16B-aligned, 2-way banks)

typedef int iv4 __attribute__((ext_vector_type(4)));
typedef __attribute__((ext_vector_type(8))) __bf16 bf16x8;
typedef __attribute__((ext_vector_type(4))) float f32x4;

// ---- bf16 helpers: h stored bf16 (row = 128 B); arithmetic fp32.
__device__ __forceinline__ float bflo(unsigned u) { return __uint_as_float(u << 16); }
__device__ __forceinline__ float bfhi(unsigned u) { return __uint_as_float(u & 0xffff0000u); }
__device__ __forceinline__ unsigned bf_rne(float f) {
    unsigned u = __float_as_uint(f);
    return (u + 0x7fffu + ((u >> 16) & 1u)) >> 16;
}
__device__ __forceinline__ unsigned pack2(float a, float b) {
    return bf_rne(a) | (bf_rne(b) << 16);
}

// ---- fused pre + hist v11: co-resident block roles, even/odd interleaved.
// v6 failed (155us): pre's 34.8KB LDS capped fused occupancy, starving hist.
// v10 failed (957us): xr[] indexed by runtime (k>>6) -> SCRATCH spill
// (VGPR_Count=40, FETCH 1.1GB). v11 fix: split xlo[16]/xhi[16] + two 64-iter
// k-loops so every array index is static; readlane's lane-select takes the
// runtime uniform k legally. ~60 VGPR, zero LDS, zero scratch.
// hist body = v3 (best, 76.5us). v4 lesson (705us): never concentrate the
// 1.6M returning atomics onto few cache lines; keep 100K deg addresses.
__global__ __launch_bounds__(256, 6) void pre_hist_kernel(
    const float* __restrict__ x, const float* __restrict__ W,
    const float* __restrict__ b, unsigned short* __restrict__ h16,
    const int* __restrict__ ei, int* __restrict__ deg, int* __restrict__ csr)
{
    const int bi = blockIdx.x;
    const int tid = threadIdx.x;
    int prei = -1, hb = -1;
    if (bi < 2 * NTILES) {
        if ((bi & 1) == 0) prei = bi >> 1;
        else hb = bi >> 1;
    } else {
        hb = NTILES + (bi - 2 * NTILES);
    }

    if (prei >= 0) {
        // ==== pre role: h0 = x @ pre_w + pre_b (bf16), reg-resident ====
        const int lane = tid & 63;
        const int wv = tid >> 6;              // wave 0..3
        const int nb = prei * 64 + wv * 16;   // this wave's 16 nodes
        float xlo[16], xhi[16], acc[16];
#pragma unroll
        for (int i = 0; i < 16; ++i) acc[i] = 0.f;
#pragma unroll
        for (int i = 0; i < 16; ++i) {
            const int node = nb + i;
            const bool ok = node < N_NODES;
            xlo[i] = ok ? x[(size_t)node * N_FEAT + lane]      : 0.f;
            xhi[i] = ok ? x[(size_t)node * N_FEAT + 64 + lane] : 0.f;
        }
        for (int k = 0; k < 64; ++k) {           // runtime loop; static xlo idx
            const float wk = W[k * N_HID + lane];    // 256B coalesced, L1-hot
#pragma unroll
            for (int i = 0; i < 16; ++i) {
                const float xk = __int_as_float(__builtin_amdgcn_readlane(
                    __float_as_int(xlo[i]), k));
                acc[i] = fmaf(xk, wk, acc[i]);
            }
        }
        for (int k = 0; k < 64; ++k) {           // second half; static xhi idx
            const float wk = W[(64 + k) * N_HID + lane];
#pragma unroll
            for (int i = 0; i < 16; ++i) {
                const float xk = __int_as_float(__builtin_amdgcn_readlane(
                    __float_as_int(xhi[i]), k));
                acc[i] = fmaf(xk, wk, acc[i]);
            }
        }
        const float bias = b[lane];
#pragma unroll
        for (int i = 0; i < 16; ++i) {
            const int node = nb + i;
            if (node < N_NODES)
                h16[(size_t)node * N_HID + lane] =
                    (unsigned short)bf_rne(acc[i] + bias);
        }
    } else {
        // ==== hist role: fixed-stride CSR fill (v3 body) ====
        const int r   = hb & (HF_GROUPS - 1);
        const int g   = hb >> 3;
        const int lo  = r * HF_RANGE;
        const int hi  = lo + HF_RANGE;
        const int t0  = g * 256 + tid;
        const iv4* dst4 = (const iv4*)(ei + N_EDGES);
        for (int q = t0; q < N_EDGES / 4; q += HF_GSZ) {
            const iv4 d = __builtin_nontemporal_load(dst4 + q);
            const int e0 = q * 4;
            if (d.x >= lo && d.x < hi) {
                int p = atomicAdd(&deg[d.x], 1);
                if (p < CSR_STRIDE)
                    csr[d.x * CSR_STRIDE + p] = __builtin_nontemporal_load(ei + e0);
            }
            if (d.y >= lo && d.y < hi) {
                int p = atomicAdd(&deg[d.y], 1);
                if (p < CSR_STRIDE)
                    csr[d.y * CSR_STRIDE + p] = __builtin_nontemporal_load(ei + e0 + 1);
            }
            if (d.z >= lo && d.z < hi) {
                int p = atomicAdd(&deg[d.z], 1);
                if (p < CSR_STRIDE)
                    csr[d.z * CSR_STRIDE + p] = __builtin_nontemporal_load(ei + e0 + 2);
            }
            if (d.w >= lo && d.w < hi) {
                int p = atomicAdd(&deg[d.w], 1);
                if (p < CSR_STRIDE)
                    csr[d.w * CSR_STRIDE + p] = __builtin_nontemporal_load(ei + e0 + 3);
            }
        }
    }
}

// ---- fused GIN layer v9 (379us best): v5 paired gather + MFMA bf16 MLP.
// MLP: per wave a 16-row block x 4 col-blocks, mfma_f32_16x16x32_bf16, K=64.
// LDS bf16: asb[128][72] (eidx staged in bytes 0..127/row, overwritten after
// that row's reads -- data-dep-safe), wsb[64][72]=W^T. 28KB total.
__global__ __launch_bounds__(512, 6) void gather_mlp_kernel(
    const uint2* __restrict__ hin, uint2* __restrict__ hout,
    const int* __restrict__ csr, const int* __restrict__ deg,
    const float* __restrict__ W1, const float* __restrict__ b1,
    const float* __restrict__ W2, const float* __restrict__ b2)
{
    __shared__ unsigned short asb[BLK_N][APITCH];  // agg/z/h bf16 (+eidx overlap)
    __shared__ unsigned short wsb[N_HID][APITCH];  // W^T bf16 [n][k]
    __shared__ int sdeg[BLK_N];
    const int tid = threadIdx.x;
    const int tx = tid & 15, ty = tid >> 4;   // ty = gather group 0..31
    const int sub = tx;
    const int n0 = blockIdx.x * BLK_N;

    // stage W1^T bf16
#pragma unroll
    for (int t = 0; t < 8; ++t) {
        const int idx = t * 512 + tid;        // 0..4095: k=idx>>6, n=idx&63
        wsb[idx & 63][idx >> 6] = (unsigned short)bf_rne(W1[idx]);
    }
    if (tid < BLK_N) {
        const int node = n0 + tid;
        sdeg[tid] = (node < N_NODES) ? deg[node] : 0;
    }
    // stage edge indices: 32 ints into bytes [0..128) of each asb row
#pragma unroll
    for (int t = 0; t < 2; ++t) {
        const int idx = t * 512 + tid;        // 0..1023 int4 slots
        const int r = idx >> 3, s4 = idx & 7;
        const int node = n0 + r;
        int4 v = make_int4(0, 0, 0, 0);
        if (node < N_NODES)
            v = *(const int4*)(csr + (size_t)node * CSR_STRIDE + s4 * 4);
        *(int4*)((char*)&asb[r][0] + s4 * 16) = v;
    }
    __syncthreads();

    // gather: group ty owns rows ty, ty+32, ty+64, ty+96; pairs (rA, rB=rA+32),
    // 16 row-loads in flight per group.
    for (int pp = 0; pp < 2; ++pp) {
        const int rA = ty + 64 * pp;
        const int rB = rA + 32;
        const int nodeA = n0 + rA;
        const int nodeB = n0 + rB;
        float aAx = 0.f, aAy = 0.f, aAz = 0.f, aAw = 0.f;
        float bAx = 0.f, bAy = 0.f, bAz = 0.f, bAw = 0.f;
        float aBx = 0.f, aBy = 0.f, aBz = 0.f, aBw = 0.f;
        float bBx = 0.f, bBy = 0.f, bBz = 0.f, bBw = 0.f;
        int nA = 0, nB = 0;
        if (nodeA < N_NODES) {
            nA = sdeg[rA]; nA = nA > CSR_STRIDE ? CSR_STRIDE : nA;
            const uint2 s = hin[(size_t)nodeA * 16 + sub];   // self term
            aAx = bflo(s.x); aAy = bfhi(s.x); aAz = bflo(s.y); aAw = bfhi(s.y);
        }
        if (nodeB < N_NODES) {
            nB = sdeg[rB]; nB = nB > CSR_STRIDE ? CSR_STRIDE : nB;
            const uint2 s = hin[(size_t)nodeB * 16 + sub];   // self term
            aBx = bflo(s.x); aBy = bfhi(s.x); aBz = bflo(s.y); aBw = bfhi(s.y);
        }
        const int nnA = nA > EMAX_LDS ? EMAX_LDS : nA;
        const int nnB = nB > EMAX_LDS ? EMAX_LDS : nB;
        const int* epA = (const int*)&asb[rA][0];
        const int* epB = (const int*)&asb[rB][0];
        const int mx = nnA > nnB ? nnA : nnB;
        for (int eb = 0; eb < mx; eb += 8) {
            uint2 rvA[8], rvB[8];
            const bool doA = eb < nnA;
            const bool doB = eb < nnB;
            if (doA) {
#pragma unroll
                for (int u = 0; u < 8; ++u) {
                    const int idx = eb + u;
                    const int cl = idx < nnA ? idx : nnA - 1;  // clamp: slots>=deg poison
                    rvA[u] = hin[(size_t)epA[cl] * 16 + sub];
                }
            }
            if (doB) {
#pragma unroll
                for (int u = 0; u < 8; ++u) {
                    const int idx = eb + u;
                    const int cl = idx < nnB ? idx : nnB - 1;
                    rvB[u] = hin[(size_t)epB[cl] * 16 + sub];
                }
            }
            if (doA) {
#pragma unroll
                for (int u = 0; u < 8; u += 2) {
                    if (eb + u < nnA) {
                        aAx += bflo(rvA[u].x); aAy += bfhi(rvA[u].x);
                        aAz += bflo(rvA[u].y); aAw += bfhi(rvA[u].y);
                    }
                    if (eb + u + 1 < nnA) {
                        bAx += bflo(rvA[u + 1].x); bAy += bfhi(rvA[u + 1].x);
                        bAz += bflo(rvA[u + 1].y); bAw += bfhi(rvA[u + 1].y);
                    }
                }
            }
            if (doB) {
#pragma unroll
                for (int u = 0; u < 8; u += 2) {
                    if (eb + u < nnB) {
                        aBx += bflo(rvB[u].x); aBy += bfhi(rvB[u].x);
                        aBz += bflo(rvB[u].y); aBw += bfhi(rvB[u].y);
                    }
                    if (eb + u + 1 < nnB) {
                        bBx += bflo(rvB[u + 1].x); bBy += bfhi(rvB[u + 1].x);
                        bBz += bflo(rvB[u + 1].y); bBw += bfhi(rvB[u + 1].y);
                    }
                }
            }
        }
        for (int t = EMAX_LDS; t < nA; ++t) { // rare tail (P~1e-4)
            const int s0 = csr[(size_t)nodeA * CSR_STRIDE + t];
            const uint2 a = hin[(size_t)s0 * 16 + sub];
            aAx += bflo(a.x); aAy += bfhi(a.x);
            aAz += bflo(a.y); aAw += bfhi(a.y);
        }
        for (int t = EMAX_LDS; t < nB; ++t) {
            const int s0 = csr[(size_t)nodeB * CSR_STRIDE + t];
            const uint2 a = hin[(size_t)s0 * 16 + sub];
            aBx += bflo(a.x); aBy += bfhi(a.x);
            aBz += bflo(a.y); aBw += bfhi(a.y);
        }
        // write agg rows bf16 (overwrites this row's eidx -- reads done)
        *(uint2*)((char*)&asb[rA][0] + sub * 8) = make_uint2(
            pack2(aAx + bAx, aAy + bAy), pack2(aAz + bAz, aAw + bAw));
        *(uint2*)((char*)&asb[rB][0] + sub * 8) = make_uint2(
            pack2(aBx + bBx, aBy + bBy), pack2(aBz + bBz, aBw + bBw));
    }
    __syncthreads();

    // ---- MFMA MLP ----
    const int wave = tid >> 6;            // row-block 0..7
    const int lane = tid & 63;
    const int lr = lane & 15;
    const int lg = lane >> 4;
    const f32x4 vzero = {0.f, 0.f, 0.f, 0.f};

    // GEMM1: z = relu(agg @ W1 + b1)
    f32x4 acc[4] = {vzero, vzero, vzero, vzero};
    {
        const char* ar = (const char*)&asb[wave * 16 + lr][0] + lg * 16;
        const bf16x8 a0 = *(const bf16x8*)ar;
        const bf16x8 a1 = *(const bf16x8*)(ar + 64);
#pragma unroll
        for (int cb = 0; cb < 4; ++cb) {
            const char* br = (const char*)&wsb[cb * 16 + lr][0] + lg * 16;
            const bf16x8 w0 = *(const bf16x8*)br;
            const bf16x8 w1 = *(const bf16x8*)(br + 64);
            acc[cb] = __builtin_amdgcn_mfma_f32_16x16x32_bf16(a0, w0, acc[cb], 0, 0, 0);
            acc[cb] = __builtin_amdgcn_mfma_f32_16x16x32_bf16(a1, w1, acc[cb], 0, 0, 0);
        }
    }
#pragma unroll
    for (int cb = 0; cb < 4; ++cb) {
        const float bias = b1[cb * 16 + lr];
#pragma unroll
        for (int rg = 0; rg < 4; ++rg) {
            const float v = fmaxf(acc[cb][rg] + bias, 0.f);
            asb[wave * 16 + lg * 4 + rg][cb * 16 + lr] = (unsigned short)bf_rne(v);
        }
    }
    __syncthreads();                       // all W1 B-frag reads done
#pragma unroll
    for (int t = 0; t < 8; ++t) {
        const int idx = t * 512 + tid;
        wsb[idx & 63][idx >> 6] = (unsigned short)bf_rne(W2[idx]);
    }
    __syncthreads();

    // GEMM2: h = relu(z @ W2 + b2)
#pragma unroll
    for (int cb = 0; cb < 4; ++cb) acc[cb] = vzero;
    {
        const char* ar = (const char*)&asb[wave * 16 + lr][0] + lg * 16;
        const bf16x8 a0 = *(const bf16x8*)ar;
        const bf16x8 a1 = *(const bf16x8*)(ar + 64);
#pragma unroll
        for (int cb = 0; cb < 4; ++cb) {
            const char* br = (const char*)&wsb[cb * 16 + lr][0] + lg * 16;
            const bf16x8 w0 = *(const bf16x8*)br;
            const bf16x8 w1 = *(const bf16x8*)(br + 64);
            acc[cb] = __builtin_amdgcn_mfma_f32_16x16x32_bf16(a0, w0, acc[cb], 0, 0, 0);
            acc[cb] = __builtin_amdgcn_mfma_f32_16x16x32_bf16(a1, w1, acc[cb], 0, 0, 0);
        }
    }
#pragma unroll
    for (int cb = 0; cb < 4; ++cb) {
        const float bias = b2[cb * 16 + lr];
#pragma unroll
        for (int rg = 0; rg < 4; ++rg) {
            const float v = fmaxf(acc[cb][rg] + bias, 0.f);
            asb[wave * 16 + lg * 4 + rg][cb * 16 + lr] = (unsigned short)bf_rne(v);
        }
    }
    __syncthreads();

    // coalesced copy-out
#pragma unroll
    for (int t = 0; t < 4; ++t) {
        const int idx = t * 512 + tid;        // 0..2047
        const int m = idx >> 4, kv = idx & 15;
        if (n0 + m < N_NODES)
            hout[(size_t)(n0 + m) * 16 + kv] =
                *(const uint2*)((const char*)&asb[m][0] + kv * 8);
    }
}

// ---- fused pool+head: block per graph; wave 0 finishes post/ro/log_softmax
// in-register from the pooled row. h is bf16. ----
__global__ __launch_bounds__(256) void pool_head_kernel(
    const unsigned short* __restrict__ h, const int* __restrict__ batch,
    const float* __restrict__ Wp, const float* __restrict__ bp,
    const float* __restrict__ Wr, const float* __restrict__ br,
    float* __restrict__ out)
{
    const int graph = blockIdx.x;
    int l = 0, r = N_NODES;
    while (l < r) { int m = (l + r) >> 1; if (batch[m] < graph) l = m + 1; else r = m; }
    const int lo = l;
    r = N_NODES;
    while (l < r) { int m = (l + r) >> 1; if (batch[m] < graph + 1) l = m + 1; else r = m; }
    const int hi = l;

    const int lane = threadIdx.x & 63;
    const int wave = threadIdx.x >> 6;
    float acc = 0.0f;
    for (int i = lo + wave; i < hi; i += 4)
        acc += __uint_as_float(((unsigned)h[(size_t)i * N_HID + lane]) << 16);
    __shared__ float sacc[4][N_HID];
    sacc[wave][lane] = acc;
    __syncthreads();
    if (wave != 0) return;

    const float gv = sacc[0][lane] + sacc[1][lane] + sacc[2][lane] + sacc[3][lane];
    float acc2 = bp[lane];
#pragma unroll
    for (int k = 0; k < N_HID; ++k) {
        const float gk = __int_as_float(
            __builtin_amdgcn_readlane(__float_as_int(gv), k));
        acc2 = fmaf(gk, Wp[k * N_HID + lane], acc2);
    }
    const float y = fmaxf(acc2, 0.f);

    float logit = (lane < N_CLASS) ? br[lane] : 0.f;
#pragma unroll
    for (int k = 0; k < N_HID; ++k) {
        const float yk = __int_as_float(
            __builtin_amdgcn_readlane(__float_as_int(y), k));
        if (lane < N_CLASS)
            logit = fmaf(yk, Wr[k * N_CLASS + lane], logit);
    }

    __shared__ float slog[N_CLASS];
    if (lane < N_CLASS) slog[lane] = logit;
    if (lane < N_CLASS) {
        float m = -INFINITY;
#pragma unroll
        for (int c = 0; c < N_CLASS; ++c) m = fmaxf(m, slog[c]);
        float sum = 0.0f;
#pragma unroll
        for (int c = 0; c < N_CLASS; ++c) sum += expf(slog[c] - m);
        out[(size_t)graph * N_CLASS + lane] = logit - m - logf(sum);
    }
}

extern "C" void kernel_launch(void* const* d_in, const int* in_sizes, int n_in,
                              void* d_out, int out_size, void* d_ws, size_t ws_size,
                              hipStream_t stream)
{
    const float* x       = (const float*)d_in[0];
    const int*   ei      = (const int*)d_in[1];   // [2, E]: row0=src, row1=dst
    const int*   batch   = (const int*)d_in[2];
    const float* pre_w   = (const float*)d_in[3];
    const float* pre_b   = (const float*)d_in[4];
    const float* conv_w1 = (const float*)d_in[5];
    const float* conv_b1 = (const float*)d_in[6];
    const float* conv_w2 = (const float*)d_in[7];
    const float* conv_b2 = (const float*)d_in[8];
    const float* post_w  = (const float*)d_in[9];
    const float* post_b  = (const float*)d_in[10];
    const float* ro_w    = (const float*)d_in[11];
    const float* ro_b    = (const float*)d_in[12];
    float* out = (float*)d_out;

    // workspace layout (~51.6 MB)
    uint2* h0   = (uint2*)d_ws;                       // 12.8 MB (bf16 h)
    uint2* h1   = h0 + (size_t)N_NODES * 16;          // 12.8 MB
    int*   deg  = (int*)(h1 + (size_t)N_NODES * 16);  // 400 KB
    int*   csr  = deg + N_NODES;                      // 25.6 MB fixed-stride

    (void)hipMemsetAsync(deg, 0, N_NODES * sizeof(int), stream);

    // fused pre + hist (zero-LDS, zero-scratch pre role)
    pre_hist_kernel<<<FUSED_BLOCKS, 256, 0, stream>>>(
        x, pre_w, pre_b, (unsigned short*)h0, ei, deg, csr);

    // 3 fused GIN layers, h ping-pong h0 -> h1 -> h0 -> h1
    gather_mlp_kernel<<<NT2, 512, 0, stream>>>(
        h0, h1, csr, deg,
        conv_w1, conv_b1, conv_w2, conv_b2);
    gather_mlp_kernel<<<NT2, 512, 0, stream>>>(
        h1, h0, csr, deg,
        conv_w1 + N_HID * N_HID, conv_b1 + N_HID,
        conv_w2 + N_HID * N_HID, conv_b2 + N_HID);
    gather_mlp_kernel<<<NT2, 512, 0, stream>>>(
        h0, h1, csr, deg,
        conv_w1 + 2 * N_HID * N_HID, conv_b1 + 2 * N_HID,
        conv_w2 + 2 * N_HID * N_HID, conv_b2 + 2 * N_HID);

    pool_head_kernel<<<N_GRAPHS, 256, 0, stream>>>(
        (const unsigned short*)h1, batch, post_w, post_b, ro_w, ro_b, out);
}

// Round 12
// 390.162 us; speedup vs baseline: 3.0868x; 1.0613x over previous
//
#include <hip/hip_runtime.h>
#include <math.h>

#define N_NODES  100000
#define N_FEAT   128
#define N_HID    64
#define N_CLASS  10
#define N_GRAPHS 1000
#define N_EDGES  1600000
#define NTILES   1563      // ceil(100000/64)   (pre kernel, 64-node tiles)
#define BLK_N    128       // gather_mlp tile
#define NT2      782       // ceil(100000/128)
#define HF_GROUPS 8        // concurrent dst ranges
#define HF_RANGE 12500     // 100000/8
#define HF_BLOCKS 2048
#define CSR_STRIDE 48      // per-node bucket; P(any of 100K Poisson(16) nodes >=48) ~3e-6
#define DEG_STRIDE 16      // one deg counter per 64B line: kills same-line atomic serialization
#define EMAX_LDS 32        // staged slots per node; P(deg>32)~1e-4 -> global tail
#define APITCH 72          // bf16 row pitch = 144 B (16B-aligned, 2-way banks)

typedef int iv4 __attribute__((ext_vector_type(4)));
typedef __attribute__((ext_vector_type(8))) __bf16 bf16x8;
typedef __attribute__((ext_vector_type(4))) float f32x4;

// ---- bf16 helpers: h stored bf16 (row = 128 B); arithmetic fp32.
__device__ __forceinline__ float bflo(unsigned u) { return __uint_as_float(u << 16); }
__device__ __forceinline__ float bfhi(unsigned u) { return __uint_as_float(u & 0xffff0000u); }
__device__ __forceinline__ unsigned bf_rne(float f) {
    unsigned u = __float_as_uint(f);
    return (u + 0x7fffu + ((u >> 16) & 1u)) >> 16;
}
__device__ __forceinline__ unsigned pack2(float a, float b) {
    return bf_rne(a) | (bf_rne(b) << 16);
}

// ---- pre (v9 serial, proven): h0 = x @ pre_w + pre_b (bf16 out).
// Overlap with hist failed 3x: v6 LDS-starved hist, v10 scratch-spilled,
// v11 readlane-VALU interfered (151us). Keep serial.
__global__ __launch_bounds__(256, 4) void pre_kernel(
    const float* __restrict__ x, const float* __restrict__ W,
    const float* __restrict__ b, uint2* __restrict__ h)
{
    __shared__ float xs[64][68];
    __shared__ float ws[64][68];
    const int tid = threadIdx.x;
    const int tx = tid & 15, ty = tid >> 4;
    const int n0 = blockIdx.x * 64;

    float acc[4][4];
#pragma unroll
    for (int i = 0; i < 4; ++i)
#pragma unroll
        for (int j = 0; j < 4; ++j) acc[i][j] = 0.f;

    for (int p = 0; p < 2; ++p) {
        __syncthreads();
#pragma unroll
        for (int t = 0; t < 4; ++t) {
            const int idx = t * 256 + tid;
            const int m = idx >> 4, kv = idx & 15;
            float4 v = make_float4(0.f, 0.f, 0.f, 0.f);
            if (n0 + m < N_NODES)
                v = *(const float4*)(x + (size_t)(n0 + m) * N_FEAT + p * 64 + kv * 4);
            *(float4*)&xs[m][kv * 4] = v;
            *(float4*)&ws[m][kv * 4] =
                *(const float4*)(W + (size_t)(p * 64 + m) * N_HID + kv * 4);
        }
        __syncthreads();
#pragma unroll 2
        for (int k4 = 0; k4 < 16; ++k4) {
            float4 a[4], bb[4];
#pragma unroll
            for (int i = 0; i < 4; ++i)
                a[i] = *(const float4*)&xs[ty + 16 * i][k4 * 4];
#pragma unroll
            for (int j = 0; j < 4; ++j)
                bb[j] = *(const float4*)&ws[k4 * 4 + j][tx * 4];
#pragma unroll
            for (int i = 0; i < 4; ++i) {
                const float* ap = (const float*)&a[i];
#pragma unroll
                for (int j = 0; j < 4; ++j) {
                    const float* bp = (const float*)&bb[j];
#pragma unroll
                    for (int c = 0; c < 4; ++c)
                        acc[i][c] = fmaf(ap[j], bp[c], acc[i][c]);
                }
            }
        }
    }

    const float4 bias = *(const float4*)(b + tx * 4);
#pragma unroll
    for (int i = 0; i < 4; ++i) {
        const int node = n0 + ty + 16 * i;
        if (node < N_NODES) {
            h[(size_t)node * 16 + tx] = make_uint2(
                pack2(acc[i][0] + bias.x, acc[i][1] + bias.y),
                pack2(acc[i][2] + bias.z, acc[i][3] + bias.w));
        }
    }
}

// ---- hist+fill v12: v3 body + deg padded to one counter per 64B line.
// Evidence chain: v4 (33K same-line atomics -> 705us) gives ~21cy per
// SERIALIZED same-line atomic; v0-v3 (256 atomics/line: 16 nodes x 16 deg)
// all land 77-86us regardless of write pattern -- consistent with per-line
// chains serializing at the L2 atomic unit. DEG_STRIDE=16 gives each node a
// private line; if different-line atomics pipeline, hist drops to ~30-45us.
// v4 lesson stands: never CONCENTRATE atomics onto fewer lines.
__global__ __launch_bounds__(256) void hist_fill_kernel(
    const int* __restrict__ ei, int* __restrict__ deg, int* __restrict__ csr)
{
    const int r   = blockIdx.x & (HF_GROUPS - 1);
    const int g   = blockIdx.x >> 3;
    const int lo  = r * HF_RANGE;
    const int hi  = lo + HF_RANGE;
    const int gsz = (gridDim.x >> 3) * blockDim.x;
    const int t0  = g * blockDim.x + threadIdx.x;
    const iv4* dst4 = (const iv4*)(ei + N_EDGES);
    for (int q = t0; q < N_EDGES / 4; q += gsz) {
        const iv4 d = __builtin_nontemporal_load(dst4 + q);
        const int e0 = q * 4;
        if (d.x >= lo && d.x < hi) {
            int p = atomicAdd(&deg[d.x * DEG_STRIDE], 1);
            if (p < CSR_STRIDE)
                csr[d.x * CSR_STRIDE + p] = __builtin_nontemporal_load(ei + e0);
        }
        if (d.y >= lo && d.y < hi) {
            int p = atomicAdd(&deg[d.y * DEG_STRIDE], 1);
            if (p < CSR_STRIDE)
                csr[d.y * CSR_STRIDE + p] = __builtin_nontemporal_load(ei + e0 + 1);
        }
        if (d.z >= lo && d.z < hi) {
            int p = atomicAdd(&deg[d.z * DEG_STRIDE], 1);
            if (p < CSR_STRIDE)
                csr[d.z * CSR_STRIDE + p] = __builtin_nontemporal_load(ei + e0 + 2);
        }
        if (d.w >= lo && d.w < hi) {
            int p = atomicAdd(&deg[d.w * DEG_STRIDE], 1);
            if (p < CSR_STRIDE)
                csr[d.w * CSR_STRIDE + p] = __builtin_nontemporal_load(ei + e0 + 3);
        }
    }
}

// ---- fused GIN layer v9 (379us best): v5 paired gather + MFMA bf16 MLP.
// MLP: per wave a 16-row block x 4 col-blocks, mfma_f32_16x16x32_bf16, K=64.
// LDS bf16: asb[128][72] (eidx staged in bytes 0..127/row, overwritten after
// that row's reads -- data-dep-safe), wsb[64][72]=W^T. 28KB total.
__global__ __launch_bounds__(512, 6) void gather_mlp_kernel(
    const uint2* __restrict__ hin, uint2* __restrict__ hout,
    const int* __restrict__ csr, const int* __restrict__ deg,
    const float* __restrict__ W1, const float* __restrict__ b1,
    const float* __restrict__ W2, const float* __restrict__ b2)
{
    __shared__ unsigned short asb[BLK_N][APITCH];  // agg/z/h bf16 (+eidx overlap)
    __shared__ unsigned short wsb[N_HID][APITCH];  // W^T bf16 [n][k]
    __shared__ int sdeg[BLK_N];
    const int tid = threadIdx.x;
    const int tx = tid & 15, ty = tid >> 4;   // ty = gather group 0..31
    const int sub = tx;
    const int n0 = blockIdx.x * BLK_N;

    // stage W1^T bf16
#pragma unroll
    for (int t = 0; t < 8; ++t) {
        const int idx = t * 512 + tid;        // 0..4095: k=idx>>6, n=idx&63
        wsb[idx & 63][idx >> 6] = (unsigned short)bf_rne(W1[idx]);
    }
    if (tid < BLK_N) {
        const int node = n0 + tid;
        sdeg[tid] = (node < N_NODES) ? deg[node * DEG_STRIDE] : 0;
    }
    // stage edge indices: 32 ints into bytes [0..128) of each asb row
#pragma unroll
    for (int t = 0; t < 2; ++t) {
        const int idx = t * 512 + tid;        // 0..1023 int4 slots
        const int r = idx >> 3, s4 = idx & 7;
        const int node = n0 + r;
        int4 v = make_int4(0, 0, 0, 0);
        if (node < N_NODES)
            v = *(const int4*)(csr + (size_t)node * CSR_STRIDE + s4 * 4);
        *(int4*)((char*)&asb[r][0] + s4 * 16) = v;
    }
    __syncthreads();

    // gather: group ty owns rows ty, ty+32, ty+64, ty+96; pairs (rA, rB=rA+32),
    // 16 row-loads in flight per group.
    for (int pp = 0; pp < 2; ++pp) {
        const int rA = ty + 64 * pp;
        const int rB = rA + 32;
        const int nodeA = n0 + rA;
        const int nodeB = n0 + rB;
        float aAx = 0.f, aAy = 0.f, aAz = 0.f, aAw = 0.f;
        float bAx = 0.f, bAy = 0.f, bAz = 0.f, bAw = 0.f;
        float aBx = 0.f, aBy = 0.f, aBz = 0.f, aBw = 0.f;
        float bBx = 0.f, bBy = 0.f, bBz = 0.f, bBw = 0.f;
        int nA = 0, nB = 0;
        if (nodeA < N_NODES) {
            nA = sdeg[rA]; nA = nA > CSR_STRIDE ? CSR_STRIDE : nA;
            const uint2 s = hin[(size_t)nodeA * 16 + sub];   // self term
            aAx = bflo(s.x); aAy = bfhi(s.x); aAz = bflo(s.y); aAw = bfhi(s.y);
        }
        if (nodeB < N_NODES) {
            nB = sdeg[rB]; nB = nB > CSR_STRIDE ? CSR_STRIDE : nB;
            const uint2 s = hin[(size_t)nodeB * 16 + sub];   // self term
            aBx = bflo(s.x); aBy = bfhi(s.x); aBz = bflo(s.y); aBw = bfhi(s.y);
        }
        const int nnA = nA > EMAX_LDS ? EMAX_LDS : nA;
        const int nnB = nB > EMAX_LDS ? EMAX_LDS : nB;
        const int* epA = (const int*)&asb[rA][0];
        const int* epB = (const int*)&asb[rB][0];
        const int mx = nnA > nnB ? nnA : nnB;
        for (int eb = 0; eb < mx; eb += 8) {
            uint2 rvA[8], rvB[8];
            const bool doA = eb < nnA;
            const bool doB = eb < nnB;
            if (doA) {
#pragma unroll
                for (int u = 0; u < 8; ++u) {
                    const int idx = eb + u;
                    const int cl = idx < nnA ? idx : nnA - 1;  // clamp: slots>=deg poison
                    rvA[u] = hin[(size_t)epA[cl] * 16 + sub];
                }
            }
            if (doB) {
#pragma unroll
                for (int u = 0; u < 8; ++u) {
                    const int idx = eb + u;
                    const int cl = idx < nnB ? idx : nnB - 1;
                    rvB[u] = hin[(size_t)epB[cl] * 16 + sub];
                }
            }
            if (doA) {
#pragma unroll
                for (int u = 0; u < 8; u += 2) {
                    if (eb + u < nnA) {
                        aAx += bflo(rvA[u].x); aAy += bfhi(rvA[u].x);
                        aAz += bflo(rvA[u].y); aAw += bfhi(rvA[u].y);
                    }
                    if (eb + u + 1 < nnA) {
                        bAx += bflo(rvA[u + 1].x); bAy += bfhi(rvA[u + 1].x);
                        bAz += bflo(rvA[u + 1].y); bAw += bfhi(rvA[u + 1].y);
                    }
                }
            }
            if (doB) {
#pragma unroll
                for (int u = 0; u < 8; u += 2) {
                    if (eb + u < nnB) {
                        aBx += bflo(rvB[u].x); aBy += bfhi(rvB[u].x);
                        aBz += bflo(rvB[u].y); aBw += bfhi(rvB[u].y);
                    }
                    if (eb + u + 1 < nnB) {
                        bBx += bflo(rvB[u + 1].x); bBy += bfhi(rvB[u + 1].x);
                        bBz += bflo(rvB[u + 1].y); bBw += bfhi(rvB[u + 1].y);
                    }
                }
            }
        }
        for (int t = EMAX_LDS; t < nA; ++t) { // rare tail (P~1e-4)
            const int s0 = csr[(size_t)nodeA * CSR_STRIDE + t];
            const uint2 a = hin[(size_t)s0 * 16 + sub];
            aAx += bflo(a.x); aAy += bfhi(a.x);
            aAz += bflo(a.y); aAw += bfhi(a.y);
        }
        for (int t = EMAX_LDS; t < nB; ++t) {
            const int s0 = csr[(size_t)nodeB * CSR_STRIDE + t];
            const uint2 a = hin[(size_t)s0 * 16 + sub];
            aBx += bflo(a.x); aBy += bfhi(a.x);
            aBz += bflo(a.y); aBw += bfhi(a.y);
        }
        // write agg rows bf16 (overwrites this row's eidx -- reads done)
        *(uint2*)((char*)&asb[rA][0] + sub * 8) = make_uint2(
            pack2(aAx + bAx, aAy + bAy), pack2(aAz + bAz, aAw + bAw));
        *(uint2*)((char*)&asb[rB][0] + sub * 8) = make_uint2(
            pack2(aBx + bBx, aBy + bBy), pack2(aBz + bBz, aBw + bBw));
    }
    __syncthreads();

    // ---- MFMA MLP ----
    const int wave = tid >> 6;            // row-block 0..7
    const int lane = tid & 63;
    const int lr = lane & 15;
    const int lg = lane >> 4;
    const f32x4 vzero = {0.f, 0.f, 0.f, 0.f};

    // GEMM1: z = relu(agg @ W1 + b1)
    f32x4 acc[4] = {vzero, vzero, vzero, vzero};
    {
        const char* ar = (const char*)&asb[wave * 16 + lr][0] + lg * 16;
        const bf16x8 a0 = *(const bf16x8*)ar;
        const bf16x8 a1 = *(const bf16x8*)(ar + 64);
#pragma unroll
        for (int cb = 0; cb < 4; ++cb) {
            const char* br = (const char*)&wsb[cb * 16 + lr][0] + lg * 16;
            const bf16x8 w0 = *(const bf16x8*)br;
            const bf16x8 w1 = *(const bf16x8*)(br + 64);
            acc[cb] = __builtin_amdgcn_mfma_f32_16x16x32_bf16(a0, w0, acc[cb], 0, 0, 0);
            acc[cb] = __builtin_amdgcn_mfma_f32_16x16x32_bf16(a1, w1, acc[cb], 0, 0, 0);
        }
    }
#pragma unroll
    for (int cb = 0; cb < 4; ++cb) {
        const float bias = b1[cb * 16 + lr];
#pragma unroll
        for (int rg = 0; rg < 4; ++rg) {
            const float v = fmaxf(acc[cb][rg] + bias, 0.f);
            asb[wave * 16 + lg * 4 + rg][cb * 16 + lr] = (unsigned short)bf_rne(v);
        }
    }
    __syncthreads();                       // all W1 B-frag reads done
#pragma unroll
    for (int t = 0; t < 8; ++t) {
        const int idx = t * 512 + tid;
        wsb[idx & 63][idx >> 6] = (unsigned short)bf_rne(W2[idx]);
    }
    __syncthreads();

    // GEMM2: h = relu(z @ W2 + b2)
#pragma unroll
    for (int cb = 0; cb < 4; ++cb) acc[cb] = vzero;
    {
        const char* ar = (const char*)&asb[wave * 16 + lr][0] + lg * 16;
        const bf16x8 a0 = *(const bf16x8*)ar;
        const bf16x8 a1 = *(const bf16x8*)(ar + 64);
#pragma unroll
        for (int cb = 0; cb < 4; ++cb) {
            const char* br = (const char*)&wsb[cb * 16 + lr][0] + lg * 16;
            const bf16x8 w0 = *(const bf16x8*)br;
            const bf16x8 w1 = *(const bf16x8*)(br + 64);
            acc[cb] = __builtin_amdgcn_mfma_f32_16x16x32_bf16(a0, w0, acc[cb], 0, 0, 0);
            acc[cb] = __builtin_amdgcn_mfma_f32_16x16x32_bf16(a1, w1, acc[cb], 0, 0, 0);
        }
    }
#pragma unroll
    for (int cb = 0; cb < 4; ++cb) {
        const float bias = b2[cb * 16 + lr];
#pragma unroll
        for (int rg = 0; rg < 4; ++rg) {
            const float v = fmaxf(acc[cb][rg] + bias, 0.f);
            asb[wave * 16 + lg * 4 + rg][cb * 16 + lr] = (unsigned short)bf_rne(v);
        }
    }
    __syncthreads();

    // coalesced copy-out
#pragma unroll
    for (int t = 0; t < 4; ++t) {
        const int idx = t * 512 + tid;        // 0..2047
        const int m = idx >> 4, kv = idx & 15;
        if (n0 + m < N_NODES)
            hout[(size_t)(n0 + m) * 16 + kv] =
                *(const uint2*)((const char*)&asb[m][0] + kv * 8);
    }
}

// ---- fused pool+head: block per graph; wave 0 finishes post/ro/log_softmax
// in-register from the pooled row. h is bf16. ----
__global__ __launch_bounds__(256) void pool_head_kernel(
    const unsigned short* __restrict__ h, const int* __restrict__ batch,
    const float* __restrict__ Wp, const float* __restrict__ bp,
    const float* __restrict__ Wr, const float* __restrict__ br,
    float* __restrict__ out)
{
    const int graph = blockIdx.x;
    int l = 0, r = N_NODES;
    while (l < r) { int m = (l + r) >> 1; if (batch[m] < graph) l = m + 1; else r = m; }
    const int lo = l;
    r = N_NODES;
    while (l < r) { int m = (l + r) >> 1; if (batch[m] < graph + 1) l = m + 1; else r = m; }
    const int hi = l;

    const int lane = threadIdx.x & 63;
    const int wave = threadIdx.x >> 6;
    float acc = 0.0f;
    for (int i = lo + wave; i < hi; i += 4)
        acc += __uint_as_float(((unsigned)h[(size_t)i * N_HID + lane]) << 16);
    __shared__ float sacc[4][N_HID];
    sacc[wave][lane] = acc;
    __syncthreads();
    if (wave != 0) return;

    const float gv = sacc[0][lane] + sacc[1][lane] + sacc[2][lane] + sacc[3][lane];
    float acc2 = bp[lane];
#pragma unroll
    for (int k = 0; k < N_HID; ++k) {
        const float gk = __int_as_float(
            __builtin_amdgcn_readlane(__float_as_int(gv), k));
        acc2 = fmaf(gk, Wp[k * N_HID + lane], acc2);
    }
    const float y = fmaxf(acc2, 0.f);

    float logit = (lane < N_CLASS) ? br[lane] : 0.f;
#pragma unroll
    for (int k = 0; k < N_HID; ++k) {
        const float yk = __int_as_float(
            __builtin_amdgcn_readlane(__float_as_int(y), k));
        if (lane < N_CLASS)
            logit = fmaf(yk, Wr[k * N_CLASS + lane], logit);
    }

    __shared__ float slog[N_CLASS];
    if (lane < N_CLASS) slog[lane] = logit;
    if (lane < N_CLASS) {
        float m = -INFINITY;
#pragma unroll
        for (int c = 0; c < N_CLASS; ++c) m = fmaxf(m, slog[c]);
        float sum = 0.0f;
#pragma unroll
        for (int c = 0; c < N_CLASS; ++c) sum += expf(slog[c] - m);
        out[(size_t)graph * N_CLASS + lane] = logit - m - logf(sum);
    }
}

extern "C" void kernel_launch(void* const* d_in, const int* in_sizes, int n_in,
                              void* d_out, int out_size, void* d_ws, size_t ws_size,
                              hipStream_t stream)
{
    const float* x       = (const float*)d_in[0];
    const int*   ei      = (const int*)d_in[1];   // [2, E]: row0=src, row1=dst
    const int*   batch   = (const int*)d_in[2];
    const float* pre_w   = (const float*)d_in[3];
    const float* pre_b   = (const float*)d_in[4];
    const float* conv_w1 = (const float*)d_in[5];
    const float* conv_b1 = (const float*)d_in[6];
    const float* conv_w2 = (const float*)d_in[7];
    const float* conv_b2 = (const float*)d_in[8];
    const float* post_w  = (const float*)d_in[9];
    const float* post_b  = (const float*)d_in[10];
    const float* ro_w    = (const float*)d_in[11];
    const float* ro_b    = (const float*)d_in[12];
    float* out = (float*)d_out;

    // workspace layout (~51.2 MB)
    uint2* h0   = (uint2*)d_ws;                       // 12.8 MB (bf16 h)
    uint2* h1   = h0 + (size_t)N_NODES * 16;          // 12.8 MB
    int*   deg  = (int*)(h1 + (size_t)N_NODES * 16);  // 6.4 MB (64B-padded counters)
    int*   csr  = deg + (size_t)N_NODES * DEG_STRIDE; // 19.2 MB (48-stride)

    (void)hipMemsetAsync(deg, 0, (size_t)N_NODES * DEG_STRIDE * sizeof(int), stream);

    pre_kernel<<<NTILES, 256, 0, stream>>>(x, pre_w, pre_b, h0);
    hist_fill_kernel<<<HF_BLOCKS, 256, 0, stream>>>(ei, deg, csr);

    // 3 fused GIN layers, h ping-pong h0 -> h1 -> h0 -> h1
    gather_mlp_kernel<<<NT2, 512, 0, stream>>>(
        h0, h1, csr, deg,
        conv_w1, conv_b1, conv_w2, conv_b2);
    gather_mlp_kernel<<<NT2, 512, 0, stream>>>(
        h1, h0, csr, deg,
        conv_w1 + N_HID * N_HID, conv_b1 + N_HID,
        conv_w2 + N_HID * N_HID, conv_b2 + N_HID);
    gather_mlp_kernel<<<NT2, 512, 0, stream>>>(
        h0, h1, csr, deg,
        conv_w1 + 2 * N_HID * N_HID, conv_b1 + 2 * N_HID,
        conv_w2 + 2 * N_HID * N_HID, conv_b2 + 2 * N_HID);

    pool_head_kernel<<<N_GRAPHS, 256, 0, stream>>>(
        (const unsigned short*)h1, batch, post_w, post_b, ro_w, ro_b, out);
}

// Round 13
// 342.828 us; speedup vs baseline: 3.5130x; 1.1381x over previous
//
#include <hip/hip_runtime.h>
#include <math.h>

#define N_NODES  100000
#define N_FEAT   128
#define N_HID    64
#define N_CLASS  10
#define N_GRAPHS 1000
#define N_EDGES  1600000
#define NTILES   1563      // ceil(100000/64)   (pre kernel, 64-node tiles)
#define BLK_N    128       // gather_mlp tile
#define NT2      782       // ceil(100000/128)
#define HF_GROUPS 8        // concurrent dst ranges
#define HF_RANGE 12500     // 100000/8
#define HF_BLOCKS 2048
#define CSR_STRIDE 64      // fixed bucket per node; P(deg>=64)~1e-20 @ Poisson(16)
#define EMAX_LDS 32        // staged slots per node; P(deg>32)~1e-4 -> global tail
#define APITCH 72          // bf16 row pitch = 144 B (16B-aligned, 2-way banks)

typedef int iv4 __attribute__((ext_vector_type(4)));
typedef __attribute__((ext_vector_type(8))) __bf16 bf16x8;
typedef __attribute__((ext_vector_type(4))) float f32x4;
typedef __attribute__((ext_vector_type(2))) float f32x2;

// ---- bf16 helpers (LDS MFMA staging + final layer): arithmetic fp32.
__device__ __forceinline__ float bflo(unsigned u) { return __uint_as_float(u << 16); }
__device__ __forceinline__ float bfhi(unsigned u) { return __uint_as_float(u & 0xffff0000u); }
__device__ __forceinline__ unsigned bf_rne(float f) {
    unsigned u = __float_as_uint(f);
    return (u + 0x7fffu + ((u >> 16) & 1u)) >> 16;
}
__device__ __forceinline__ unsigned pack2(float a, float b) {
    return bf_rne(a) | (bf_rne(b) << 16);
}

// ---- fp8 e4m3 pack/unpack via HW converters (2 vals/inst). Self-consistent
// encode+decode (same HW interpretation both ways).
__device__ __forceinline__ unsigned pack_fp8x4(float a, float b, float c, float d) {
    int p = __builtin_amdgcn_cvt_pk_fp8_f32(a, b, 0, false);
    p = __builtin_amdgcn_cvt_pk_fp8_f32(c, d, p, true);
    return (unsigned)p;
}

// ---- pre: h0 = x @ pre_w + pre_b (fp8 out). Serial before hist: overlap
// failed 3x (v6 LDS-starve, v10 scratch, v11 readlane-VALU interference).
__global__ __launch_bounds__(256, 4) void pre_kernel(
    const float* __restrict__ x, const float* __restrict__ W,
    const float* __restrict__ b, unsigned* __restrict__ hq)
{
    __shared__ float xs[64][68];
    __shared__ float ws[64][68];
    const int tid = threadIdx.x;
    const int tx = tid & 15, ty = tid >> 4;
    const int n0 = blockIdx.x * 64;

    float acc[4][4];
#pragma unroll
    for (int i = 0; i < 4; ++i)
#pragma unroll
        for (int j = 0; j < 4; ++j) acc[i][j] = 0.f;

    for (int p = 0; p < 2; ++p) {
        __syncthreads();
#pragma unroll
        for (int t = 0; t < 4; ++t) {
            const int idx = t * 256 + tid;
            const int m = idx >> 4, kv = idx & 15;
            float4 v = make_float4(0.f, 0.f, 0.f, 0.f);
            if (n0 + m < N_NODES)
                v = *(const float4*)(x + (size_t)(n0 + m) * N_FEAT + p * 64 + kv * 4);
            *(float4*)&xs[m][kv * 4] = v;
            *(float4*)&ws[m][kv * 4] =
                *(const float4*)(W + (size_t)(p * 64 + m) * N_HID + kv * 4);
        }
        __syncthreads();
#pragma unroll 2
        for (int k4 = 0; k4 < 16; ++k4) {
            float4 a[4], bb[4];
#pragma unroll
            for (int i = 0; i < 4; ++i)
                a[i] = *(const float4*)&xs[ty + 16 * i][k4 * 4];
#pragma unroll
            for (int j = 0; j < 4; ++j)
                bb[j] = *(const float4*)&ws[k4 * 4 + j][tx * 4];
#pragma unroll
            for (int i = 0; i < 4; ++i) {
                const float* ap = (const float*)&a[i];
#pragma unroll
                for (int j = 0; j < 4; ++j) {
                    const float* bp = (const float*)&bb[j];
#pragma unroll
                    for (int c = 0; c < 4; ++c)
                        acc[i][c] = fmaf(ap[j], bp[c], acc[i][c]);
                }
            }
        }
    }

    const float4 bias = *(const float4*)(b + tx * 4);
#pragma unroll
    for (int i = 0; i < 4; ++i) {
        const int node = n0 + ty + 16 * i;
        if (node < N_NODES) {
            hq[(size_t)node * 16 + tx] = pack_fp8x4(
                acc[i][0] + bias.x, acc[i][1] + bias.y,
                acc[i][2] + bias.z, acc[i][3] + bias.w);
        }
    }
}

// ---- hist+fill (v9 config, the measured 77us floor): 8 concurrent
// dst-ranges, NT dst+src reads, atomics spread over 100K deg addresses.
// CLOSED after 5 falsifications: v0-v3 write-pattern changes (92/79/66MB)
// all 77-86us; v4 bucketize (few-line atomics) 705us; v12 line-padded deg
// 87-89us. Floor = fabric atomic/latency throughput (~10 returning
// atomics/cycle chip-wide). Do not touch.
__global__ __launch_bounds__(256) void hist_fill_kernel(
    const int* __restrict__ ei, int* __restrict__ deg, int* __restrict__ csr)
{
    const int r   = blockIdx.x & (HF_GROUPS - 1);
    const int g   = blockIdx.x >> 3;
    const int lo  = r * HF_RANGE;
    const int hi  = lo + HF_RANGE;
    const int gsz = (gridDim.x >> 3) * blockDim.x;
    const int t0  = g * blockDim.x + threadIdx.x;
    const iv4* dst4 = (const iv4*)(ei + N_EDGES);
    for (int q = t0; q < N_EDGES / 4; q += gsz) {
        const iv4 d = __builtin_nontemporal_load(dst4 + q);
        const int e0 = q * 4;
        if (d.x >= lo && d.x < hi) {
            int p = atomicAdd(&deg[d.x], 1);
            if (p < CSR_STRIDE)
                csr[d.x * CSR_STRIDE + p] = __builtin_nontemporal_load(ei + e0);
        }
        if (d.y >= lo && d.y < hi) {
            int p = atomicAdd(&deg[d.y], 1);
            if (p < CSR_STRIDE)
                csr[d.y * CSR_STRIDE + p] = __builtin_nontemporal_load(ei + e0 + 1);
        }
        if (d.z >= lo && d.z < hi) {
            int p = atomicAdd(&deg[d.z], 1);
            if (p < CSR_STRIDE)
                csr[d.z * CSR_STRIDE + p] = __builtin_nontemporal_load(ei + e0 + 2);
        }
        if (d.w >= lo && d.w < hi) {
            int p = atomicAdd(&deg[d.w], 1);
            if (p < CSR_STRIDE)
                csr[d.w * CSR_STRIDE + p] = __builtin_nontemporal_load(ei + e0 + 3);
        }
    }
}

// ---- fused GIN layer v13: fp8 gather + MFMA bf16 MLP.
// v9 analysis: gather is random-LINE-bound (3.2M lines/layer at ~58M
// lines/s). fp8 h row = 64B = ONE line (16 lanes x u32, perfectly
// coalesced) -> half the lines. Decode = 2 HW cvt/row/lane. agg stays fp32
// in registers -> bf16 LDS -> MFMA (unchanged). FP8OUT: intermediate
// layers emit fp8; final layer emits bf16 for pool_head.
template <bool FP8OUT>
__global__ __launch_bounds__(512, 6) void gather_mlp_kernel(
    const unsigned* __restrict__ hin, unsigned* __restrict__ hq_out,
    uint2* __restrict__ hbf_out,
    const int* __restrict__ csr, const int* __restrict__ deg,
    const float* __restrict__ W1, const float* __restrict__ b1,
    const float* __restrict__ W2, const float* __restrict__ b2)
{
    __shared__ unsigned short asb[BLK_N][APITCH];  // agg/z/h bf16 (+eidx overlap)
    __shared__ unsigned short wsb[N_HID][APITCH];  // W^T bf16 [n][k]
    __shared__ int sdeg[BLK_N];
    const int tid = threadIdx.x;
    const int tx = tid & 15, ty = tid >> 4;   // ty = gather group 0..31
    const int sub = tx;
    const int n0 = blockIdx.x * BLK_N;

    // stage W1^T bf16
#pragma unroll
    for (int t = 0; t < 8; ++t) {
        const int idx = t * 512 + tid;        // 0..4095: k=idx>>6, n=idx&63
        wsb[idx & 63][idx >> 6] = (unsigned short)bf_rne(W1[idx]);
    }
    if (tid < BLK_N) {
        const int node = n0 + tid;
        sdeg[tid] = (node < N_NODES) ? deg[node] : 0;
    }
    // stage edge indices: 32 ints into bytes [0..128) of each asb row
#pragma unroll
    for (int t = 0; t < 2; ++t) {
        const int idx = t * 512 + tid;        // 0..1023 int4 slots
        const int r = idx >> 3, s4 = idx & 7;
        const int node = n0 + r;
        int4 v = make_int4(0, 0, 0, 0);
        if (node < N_NODES)
            v = *(const int4*)(csr + (size_t)node * CSR_STRIDE + s4 * 4);
        *(int4*)((char*)&asb[r][0] + s4 * 16) = v;
    }
    __syncthreads();

    // gather: group ty owns rows ty, ty+32, ty+64, ty+96; pairs (rA, rB=rA+32),
    // 16 row-loads in flight per group. Rows are fp8: one u32 per lane.
    for (int pp = 0; pp < 2; ++pp) {
        const int rA = ty + 64 * pp;
        const int rB = rA + 32;
        const int nodeA = n0 + rA;
        const int nodeB = n0 + rB;
        float aAx = 0.f, aAy = 0.f, aAz = 0.f, aAw = 0.f;
        float bAx = 0.f, bAy = 0.f, bAz = 0.f, bAw = 0.f;
        float aBx = 0.f, aBy = 0.f, aBz = 0.f, aBw = 0.f;
        float bBx = 0.f, bBy = 0.f, bBz = 0.f, bBw = 0.f;
        int nA = 0, nB = 0;
        if (nodeA < N_NODES) {
            nA = sdeg[rA]; nA = nA > CSR_STRIDE ? CSR_STRIDE : nA;
            const unsigned s = hin[(size_t)nodeA * 16 + sub];   // self term
            const f32x2 lo = __builtin_amdgcn_cvt_pk_f32_fp8((int)s, false);
            const f32x2 hi = __builtin_amdgcn_cvt_pk_f32_fp8((int)s, true);
            aAx = lo.x; aAy = lo.y; aAz = hi.x; aAw = hi.y;
        }
        if (nodeB < N_NODES) {
            nB = sdeg[rB]; nB = nB > CSR_STRIDE ? CSR_STRIDE : nB;
            const unsigned s = hin[(size_t)nodeB * 16 + sub];   // self term
            const f32x2 lo = __builtin_amdgcn_cvt_pk_f32_fp8((int)s, false);
            const f32x2 hi = __builtin_amdgcn_cvt_pk_f32_fp8((int)s, true);
            aBx = lo.x; aBy = lo.y; aBz = hi.x; aBw = hi.y;
        }
        const int nnA = nA > EMAX_LDS ? EMAX_LDS : nA;
        const int nnB = nB > EMAX_LDS ? EMAX_LDS : nB;
        const int* epA = (const int*)&asb[rA][0];
        const int* epB = (const int*)&asb[rB][0];
        const int mx = nnA > nnB ? nnA : nnB;
        for (int eb = 0; eb < mx; eb += 8) {
            unsigned rvA[8], rvB[8];
            const bool doA = eb < nnA;
            const bool doB = eb < nnB;
            if (doA) {
#pragma unroll
                for (int u = 0; u < 8; ++u) {
                    const int idx = eb + u;
                    const int cl = idx < nnA ? idx : nnA - 1;  // clamp: slots>=deg poison
                    rvA[u] = hin[(size_t)epA[cl] * 16 + sub];
                }
            }
            if (doB) {
#pragma unroll
                for (int u = 0; u < 8; ++u) {
                    const int idx = eb + u;
                    const int cl = idx < nnB ? idx : nnB - 1;
                    rvB[u] = hin[(size_t)epB[cl] * 16 + sub];
                }
            }
            if (doA) {
#pragma unroll
                for (int u = 0; u < 8; u += 2) {
                    if (eb + u < nnA) {
                        const f32x2 lo = __builtin_amdgcn_cvt_pk_f32_fp8((int)rvA[u], false);
                        const f32x2 hi = __builtin_amdgcn_cvt_pk_f32_fp8((int)rvA[u], true);
                        aAx += lo.x; aAy += lo.y; aAz += hi.x; aAw += hi.y;
                    }
                    if (eb + u + 1 < nnA) {
                        const f32x2 lo = __builtin_amdgcn_cvt_pk_f32_fp8((int)rvA[u + 1], false);
                        const f32x2 hi = __builtin_amdgcn_cvt_pk_f32_fp8((int)rvA[u + 1], true);
                        bAx += lo.x; bAy += lo.y; bAz += hi.x; bAw += hi.y;
                    }
                }
            }
            if (doB) {
#pragma unroll
                for (int u = 0; u < 8; u += 2) {
                    if (eb + u < nnB) {
                        const f32x2 lo = __builtin_amdgcn_cvt_pk_f32_fp8((int)rvB[u], false);
                        const f32x2 hi = __builtin_amdgcn_cvt_pk_f32_fp8((int)rvB[u], true);
                        aBx += lo.x; aBy += lo.y; aBz += hi.x; aBw += hi.y;
                    }
                    if (eb + u + 1 < nnB) {
                        const f32x2 lo = __builtin_amdgcn_cvt_pk_f32_fp8((int)rvB[u + 1], false);
                        const f32x2 hi = __builtin_amdgcn_cvt_pk_f32_fp8((int)rvB[u + 1], true);
                        bBx += lo.x; bBy += lo.y; bBz += hi.x; bBw += hi.y;
                    }
                }
            }
        }
        for (int t = EMAX_LDS; t < nA; ++t) { // rare tail (P~1e-4)
            const int s0 = csr[(size_t)nodeA * CSR_STRIDE + t];
            const unsigned a = hin[(size_t)s0 * 16 + sub];
            const f32x2 lo = __builtin_amdgcn_cvt_pk_f32_fp8((int)a, false);
            const f32x2 hi = __builtin_amdgcn_cvt_pk_f32_fp8((int)a, true);
            aAx += lo.x; aAy += lo.y; aAz += hi.x; aAw += hi.y;
        }
        for (int t = EMAX_LDS; t < nB; ++t) {
            const int s0 = csr[(size_t)nodeB * CSR_STRIDE + t];
            const unsigned a = hin[(size_t)s0 * 16 + sub];
            const f32x2 lo = __builtin_amdgcn_cvt_pk_f32_fp8((int)a, false);
            const f32x2 hi = __builtin_amdgcn_cvt_pk_f32_fp8((int)a, true);
            aBx += lo.x; aBy += lo.y; aBz += hi.x; aBw += hi.y;
        }
        // write agg rows bf16 (overwrites this row's eidx -- reads done)
        *(uint2*)((char*)&asb[rA][0] + sub * 8) = make_uint2(
            pack2(aAx + bAx, aAy + bAy), pack2(aAz + bAz, aAw + bAw));
        *(uint2*)((char*)&asb[rB][0] + sub * 8) = make_uint2(
            pack2(aBx + bBx, aBy + bBy), pack2(aBz + bBz, aBw + bBw));
    }
    __syncthreads();

    // ---- MFMA MLP ----
    const int wave = tid >> 6;            // row-block 0..7
    const int lane = tid & 63;
    const int lr = lane & 15;
    const int lg = lane >> 4;
    const f32x4 vzero = {0.f, 0.f, 0.f, 0.f};

    // GEMM1: z = relu(agg @ W1 + b1)
    f32x4 acc[4] = {vzero, vzero, vzero, vzero};
    {
        const char* ar = (const char*)&asb[wave * 16 + lr][0] + lg * 16;
        const bf16x8 a0 = *(const bf16x8*)ar;
        const bf16x8 a1 = *(const bf16x8*)(ar + 64);
#pragma unroll
        for (int cb = 0; cb < 4; ++cb) {
            const char* br = (const char*)&wsb[cb * 16 + lr][0] + lg * 16;
            const bf16x8 w0 = *(const bf16x8*)br;
            const bf16x8 w1 = *(const bf16x8*)(br + 64);
            acc[cb] = __builtin_amdgcn_mfma_f32_16x16x32_bf16(a0, w0, acc[cb], 0, 0, 0);
            acc[cb] = __builtin_amdgcn_mfma_f32_16x16x32_bf16(a1, w1, acc[cb], 0, 0, 0);
        }
    }
#pragma unroll
    for (int cb = 0; cb < 4; ++cb) {
        const float bias = b1[cb * 16 + lr];
#pragma unroll
        for (int rg = 0; rg < 4; ++rg) {
            const float v = fmaxf(acc[cb][rg] + bias, 0.f);
            asb[wave * 16 + lg * 4 + rg][cb * 16 + lr] = (unsigned short)bf_rne(v);
        }
    }
    __syncthreads();                       // all W1 B-frag reads done
#pragma unroll
    for (int t = 0; t < 8; ++t) {
        const int idx = t * 512 + tid;
        wsb[idx & 63][idx >> 6] = (unsigned short)bf_rne(W2[idx]);
    }
    __syncthreads();

    // GEMM2: h = relu(z @ W2 + b2)
#pragma unroll
    for (int cb = 0; cb < 4; ++cb) acc[cb] = vzero;
    {
        const char* ar = (const char*)&asb[wave * 16 + lr][0] + lg * 16;
        const bf16x8 a0 = *(const bf16x8*)ar;
        const bf16x8 a1 = *(const bf16x8*)(ar + 64);
#pragma unroll
        for (int cb = 0; cb < 4; ++cb) {
            const char* br = (const char*)&wsb[cb * 16 + lr][0] + lg * 16;
            const bf16x8 w0 = *(const bf16x8*)br;
            const bf16x8 w1 = *(const bf16x8*)(br + 64);
            acc[cb] = __builtin_amdgcn_mfma_f32_16x16x32_bf16(a0, w0, acc[cb], 0, 0, 0);
            acc[cb] = __builtin_amdgcn_mfma_f32_16x16x32_bf16(a1, w1, acc[cb], 0, 0, 0);
        }
    }
#pragma unroll
    for (int cb = 0; cb < 4; ++cb) {
        const float bias = b2[cb * 16 + lr];
#pragma unroll
        for (int rg = 0; rg < 4; ++rg) {
            const float v = fmaxf(acc[cb][rg] + bias, 0.f);
            asb[wave * 16 + lg * 4 + rg][cb * 16 + lr] = (unsigned short)bf_rne(v);
        }
    }
    __syncthreads();

    // coalesced copy-out: fp8 (intermediate layers) or bf16 (final layer)
#pragma unroll
    for (int t = 0; t < 4; ++t) {
        const int idx = t * 512 + tid;        // 0..2047
        const int m = idx >> 4, kv = idx & 15;
        if (n0 + m < N_NODES) {
            const uint2 v = *(const uint2*)((const char*)&asb[m][0] + kv * 8);
            if (FP8OUT) {
                hq_out[(size_t)(n0 + m) * 16 + kv] = pack_fp8x4(
                    bflo(v.x), bfhi(v.x), bflo(v.y), bfhi(v.y));
            } else {
                hbf_out[(size_t)(n0 + m) * 16 + kv] = v;
            }
        }
    }
}

// ---- fused pool+head: block per graph; wave 0 finishes post/ro/log_softmax
// in-register from the pooled row. Final h is bf16. ----
__global__ __launch_bounds__(256) void pool_head_kernel(
    const unsigned short* __restrict__ h, const int* __restrict__ batch,
    const float* __restrict__ Wp, const float* __restrict__ bp,
    const float* __restrict__ Wr, const float* __restrict__ br,
    float* __restrict__ out)
{
    const int graph = blockIdx.x;
    int l = 0, r = N_NODES;
    while (l < r) { int m = (l + r) >> 1; if (batch[m] < graph) l = m + 1; else r = m; }
    const int lo = l;
    r = N_NODES;
    while (l < r) { int m = (l + r) >> 1; if (batch[m] < graph + 1) l = m + 1; else r = m; }
    const int hi = l;

    const int lane = threadIdx.x & 63;
    const int wave = threadIdx.x >> 6;
    float acc = 0.0f;
    for (int i = lo + wave; i < hi; i += 4)
        acc += __uint_as_float(((unsigned)h[(size_t)i * N_HID + lane]) << 16);
    __shared__ float sacc[4][N_HID];
    sacc[wave][lane] = acc;
    __syncthreads();
    if (wave != 0) return;

    const float gv = sacc[0][lane] + sacc[1][lane] + sacc[2][lane] + sacc[3][lane];
    float acc2 = bp[lane];
#pragma unroll
    for (int k = 0; k < N_HID; ++k) {
        const float gk = __int_as_float(
            __builtin_amdgcn_readlane(__float_as_int(gv), k));
        acc2 = fmaf(gk, Wp[k * N_HID + lane], acc2);
    }
    const float y = fmaxf(acc2, 0.f);

    float logit = (lane < N_CLASS) ? br[lane] : 0.f;
#pragma unroll
    for (int k = 0; k < N_HID; ++k) {
        const float yk = __int_as_float(
            __builtin_amdgcn_readlane(__float_as_int(y), k));
        if (lane < N_CLASS)
            logit = fmaf(yk, Wr[k * N_CLASS + lane], logit);
    }

    __shared__ float slog[N_CLASS];
    if (lane < N_CLASS) slog[lane] = logit;
    if (lane < N_CLASS) {
        float m = -INFINITY;
#pragma unroll
        for (int c = 0; c < N_CLASS; ++c) m = fmaxf(m, slog[c]);
        float sum = 0.0f;
#pragma unroll
        for (int c = 0; c < N_CLASS; ++c) sum += expf(slog[c] - m);
        out[(size_t)graph * N_CLASS + lane] = logit - m - logf(sum);
    }
}

extern "C" void kernel_launch(void* const* d_in, const int* in_sizes, int n_in,
                              void* d_out, int out_size, void* d_ws, size_t ws_size,
                              hipStream_t stream)
{
    const float* x       = (const float*)d_in[0];
    const int*   ei      = (const int*)d_in[1];   // [2, E]: row0=src, row1=dst
    const int*   batch   = (const int*)d_in[2];
    const float* pre_w   = (const float*)d_in[3];
    const float* pre_b   = (const float*)d_in[4];
    const float* conv_w1 = (const float*)d_in[5];
    const float* conv_b1 = (const float*)d_in[6];
    const float* conv_w2 = (const float*)d_in[7];
    const float* conv_b2 = (const float*)d_in[8];
    const float* post_w  = (const float*)d_in[9];
    const float* post_b  = (const float*)d_in[10];
    const float* ro_w    = (const float*)d_in[11];
    const float* ro_b    = (const float*)d_in[12];
    float* out = (float*)d_out;

    // workspace layout (~51.6 MB)
    unsigned* hq0 = (unsigned*)d_ws;                    // 6.4 MB (fp8 h, 64B rows)
    unsigned* hq1 = hq0 + (size_t)N_NODES * 16;         // 6.4 MB
    uint2*    hbf = (uint2*)(hq1 + (size_t)N_NODES * 16); // 12.8 MB (bf16 final h)
    int*      deg = (int*)(hbf + (size_t)N_NODES * 16); // 400 KB
    int*      csr = deg + N_NODES;                      // 25.6 MB fixed-stride

    (void)hipMemsetAsync(deg, 0, N_NODES * sizeof(int), stream);

    pre_kernel<<<NTILES, 256, 0, stream>>>(x, pre_w, pre_b, hq0);
    hist_fill_kernel<<<HF_BLOCKS, 256, 0, stream>>>(ei, deg, csr);

    // 3 fused GIN layers: fp8 ping-pong hq0 -> hq1 -> hq0; final -> bf16 hbf
    gather_mlp_kernel<true><<<NT2, 512, 0, stream>>>(
        hq0, hq1, (uint2*)nullptr, csr, deg,
        conv_w1, conv_b1, conv_w2, conv_b2);
    gather_mlp_kernel<true><<<NT2, 512, 0, stream>>>(
        hq1, hq0, (uint2*)nullptr, csr, deg,
        conv_w1 + N_HID * N_HID, conv_b1 + N_HID,
        conv_w2 + N_HID * N_HID, conv_b2 + N_HID);
    gather_mlp_kernel<false><<<NT2, 512, 0, stream>>>(
        hq0, (unsigned*)nullptr, hbf, csr, deg,
        conv_w1 + 2 * N_HID * N_HID, conv_b1 + 2 * N_HID,
        conv_w2 + 2 * N_HID * N_HID, conv_b2 + 2 * N_HID);

    pool_head_kernel<<<N_GRAPHS, 256, 0, stream>>>(
        (const unsigned short*)hbf, batch, post_w, post_b, ro_w, ro_b, out);
}

// Round 14
// 332.353 us; speedup vs baseline: 3.6237x; 1.0315x over previous
//
#include <hip/hip_runtime.h>
#include <math.h>

#define N_NODES  100000
#define N_FEAT   128
#define N_HID    64
#define N_CLASS  10
#define N_GRAPHS 1000
#define NTILES   1563      // ceil(100000/64)   (pre kernel, 64-node tiles)
#define N_EDGES  1600000
#define BLK_N    128       // gather_mlp tile
#define NT2      782       // ceil(100000/128)
#define HF_GROUPS 8        // concurrent dst ranges
#define HF_RANGE 12500     // 100000/8
#define HF_BLOCKS 2048
#define CSR_STRIDE 64      // fixed bucket per node; P(deg>=64)~1e-20 @ Poisson(16)
#define EMAX_LDS 32        // staged slots per node; P(deg>32)~1e-4 -> global tail
#define APITCH 72          // bf16 row pitch = 144 B (16B-aligned, 2-way banks)
#define PWPITCH 136        // pre: bf16 row pitch = 272 B for K=128 rows

typedef int iv4 __attribute__((ext_vector_type(4)));
typedef __attribute__((ext_vector_type(8))) __bf16 bf16x8;
typedef __attribute__((ext_vector_type(4))) float f32x4;
typedef __attribute__((ext_vector_type(2))) float f32x2;

// ---- bf16 helpers (LDS MFMA staging + final layer): arithmetic fp32.
__device__ __forceinline__ float bflo(unsigned u) { return __uint_as_float(u << 16); }
__device__ __forceinline__ float bfhi(unsigned u) { return __uint_as_float(u & 0xffff0000u); }
__device__ __forceinline__ unsigned bf_rne(float f) {
    unsigned u = __float_as_uint(f);
    return (u + 0x7fffu + ((u >> 16) & 1u)) >> 16;
}
__device__ __forceinline__ unsigned pack2(float a, float b) {
    return bf_rne(a) | (bf_rne(b) << 16);
}

// ---- fp8 e4m3 pack/unpack via HW converters (2 vals/inst). Self-consistent
// encode+decode (same HW interpretation both ways).
__device__ __forceinline__ unsigned pack_fp8x4(float a, float b, float c, float d) {
    int p = __builtin_amdgcn_cvt_pk_fp8_f32(a, b, 0, false);
    p = __builtin_amdgcn_cvt_pk_fp8_f32(c, d, p, true);
    return (unsigned)p;
}

// ---- pre v14: MFMA bf16 GEMM (was fp32 VALU, ~20-25us; VALU floor 10us).
// 64-node tile, K=128 = 4 MFMA K-steps x 4 col-blocks per wave. x and W^T
// staged bf16 in LDS (272B pitch = 2-way banks, free). Output fp8 via
// transpose-through-LDS copy-out. bf16 x adds ~0.4% rel err -- negligible
// vs the fp8 h0 quantization already applied.
// Serial before hist: overlap failed 3x (v6 LDS-starve, v10 scratch,
// v11 readlane-VALU interference).
__global__ __launch_bounds__(256, 4) void pre_kernel(
    const float* __restrict__ x, const float* __restrict__ W,
    const float* __restrict__ b, unsigned* __restrict__ hq)
{
    __shared__ unsigned short xsb[64][PWPITCH];   // x tile bf16; reused for out
    __shared__ unsigned short wsb[64][PWPITCH];   // W^T bf16 [n][k]
    const int tid = threadIdx.x;
    const int n0 = blockIdx.x * 64;

    // stage W^T bf16: idx = k*64+n (coalesced read) -> wsb[n][k]
#pragma unroll
    for (int t = 0; t < 32; ++t) {
        const int idx = t * 256 + tid;   // 0..8191
        wsb[idx & 63][idx >> 6] = (unsigned short)bf_rne(W[idx]);
    }
    // stage x tile bf16: 64 rows x 128 cols (float4 coalesced)
#pragma unroll
    for (int t = 0; t < 8; ++t) {
        const int idx = t * 256 + tid;   // 0..2047 float4 slots (32/row)
        const int m = idx >> 5, c4 = idx & 31;
        float4 v = make_float4(0.f, 0.f, 0.f, 0.f);
        if (n0 + m < N_NODES)
            v = *(const float4*)(x + (size_t)(n0 + m) * N_FEAT + c4 * 4);
        xsb[m][c4 * 4 + 0] = (unsigned short)bf_rne(v.x);
        xsb[m][c4 * 4 + 1] = (unsigned short)bf_rne(v.y);
        xsb[m][c4 * 4 + 2] = (unsigned short)bf_rne(v.z);
        xsb[m][c4 * 4 + 3] = (unsigned short)bf_rne(v.w);
    }
    __syncthreads();

    const int wave = tid >> 6;       // rows wave*16..+15
    const int lane = tid & 63;
    const int lr = lane & 15, lg = lane >> 4;
    const f32x4 vzero = {0.f, 0.f, 0.f, 0.f};
    f32x4 acc[4] = {vzero, vzero, vzero, vzero};
#pragma unroll
    for (int s = 0; s < 4; ++s) {     // K-steps of 32
        const char* ar = (const char*)&xsb[wave * 16 + lr][s * 32] + lg * 16;
        const bf16x8 a0 = *(const bf16x8*)ar;
#pragma unroll
        for (int cb = 0; cb < 4; ++cb) {
            const char* br = (const char*)&wsb[cb * 16 + lr][s * 32] + lg * 16;
            const bf16x8 w0 = *(const bf16x8*)br;
            acc[cb] = __builtin_amdgcn_mfma_f32_16x16x32_bf16(a0, w0, acc[cb], 0, 0, 0);
        }
    }
    __syncthreads();   // all xsb/wsb frag reads done; reuse xsb for output
#pragma unroll
    for (int cb = 0; cb < 4; ++cb) {
        const float bias = b[cb * 16 + lr];
#pragma unroll
        for (int rg = 0; rg < 4; ++rg) {
            const float v = acc[cb][rg] + bias;   // no relu in pre
            xsb[wave * 16 + lg * 4 + rg][cb * 16 + lr] = (unsigned short)bf_rne(v);
        }
    }
    __syncthreads();
    // copy-out fp8 (coalesced u32 per lane)
#pragma unroll
    for (int t = 0; t < 4; ++t) {
        const int idx = t * 256 + tid;   // 0..1023
        const int m = idx >> 4, kv = idx & 15;
        if (n0 + m < N_NODES) {
            const unsigned short* p = &xsb[m][kv * 4];
            hq[(size_t)(n0 + m) * 16 + kv] = pack_fp8x4(
                bflo(p[0]), bflo(p[1]), bflo(p[2]), bflo(p[3]));
        }
    }
}

// ---- hist+fill (v9 config, the measured 77us floor): 8 concurrent
// dst-ranges, NT dst+src reads, atomics spread over 100K deg addresses.
// CLOSED after 5 falsifications: v0-v3 write-pattern changes (92/79/66MB)
// all 77-86us; v4 bucketize (few-line atomics) 705us; v12 line-padded deg
// 87-89us. Floor = fabric atomic/latency throughput. Do not touch.
__global__ __launch_bounds__(256) void hist_fill_kernel(
    const int* __restrict__ ei, int* __restrict__ deg, int* __restrict__ csr)
{
    const int r   = blockIdx.x & (HF_GROUPS - 1);
    const int g   = blockIdx.x >> 3;
    const int lo  = r * HF_RANGE;
    const int hi  = lo + HF_RANGE;
    const int gsz = (gridDim.x >> 3) * blockDim.x;
    const int t0  = g * blockDim.x + threadIdx.x;
    const iv4* dst4 = (const iv4*)(ei + N_EDGES);
    for (int q = t0; q < N_EDGES / 4; q += gsz) {
        const iv4 d = __builtin_nontemporal_load(dst4 + q);
        const int e0 = q * 4;
        if (d.x >= lo && d.x < hi) {
            int p = atomicAdd(&deg[d.x], 1);
            if (p < CSR_STRIDE)
                csr[d.x * CSR_STRIDE + p] = __builtin_nontemporal_load(ei + e0);
        }
        if (d.y >= lo && d.y < hi) {
            int p = atomicAdd(&deg[d.y], 1);
            if (p < CSR_STRIDE)
                csr[d.y * CSR_STRIDE + p] = __builtin_nontemporal_load(ei + e0 + 1);
        }
        if (d.z >= lo && d.z < hi) {
            int p = atomicAdd(&deg[d.z], 1);
            if (p < CSR_STRIDE)
                csr[d.z * CSR_STRIDE + p] = __builtin_nontemporal_load(ei + e0 + 2);
        }
        if (d.w >= lo && d.w < hi) {
            int p = atomicAdd(&deg[d.w], 1);
            if (p < CSR_STRIDE)
                csr[d.w * CSR_STRIDE + p] = __builtin_nontemporal_load(ei + e0 + 3);
        }
    }
}

// ---- fused GIN layer v13 (342.8us best): fp8 gather + MFMA bf16 MLP.
// gather is random-LINE-bound; fp8 row = 64B = one line (half of bf16).
// agg fp32 in regs -> bf16 LDS -> MFMA. FP8OUT: intermediate layers emit
// fp8; final layer emits bf16 for pool_head.
template <bool FP8OUT>
__global__ __launch_bounds__(512, 6) void gather_mlp_kernel(
    const unsigned* __restrict__ hin, unsigned* __restrict__ hq_out,
    uint2* __restrict__ hbf_out,
    const int* __restrict__ csr, const int* __restrict__ deg,
    const float* __restrict__ W1, const float* __restrict__ b1,
    const float* __restrict__ W2, const float* __restrict__ b2)
{
    __shared__ unsigned short asb[BLK_N][APITCH];  // agg/z/h bf16 (+eidx overlap)
    __shared__ unsigned short wsb[N_HID][APITCH];  // W^T bf16 [n][k]
    __shared__ int sdeg[BLK_N];
    const int tid = threadIdx.x;
    const int tx = tid & 15, ty = tid >> 4;   // ty = gather group 0..31
    const int sub = tx;
    const int n0 = blockIdx.x * BLK_N;

    // stage W1^T bf16
#pragma unroll
    for (int t = 0; t < 8; ++t) {
        const int idx = t * 512 + tid;        // 0..4095: k=idx>>6, n=idx&63
        wsb[idx & 63][idx >> 6] = (unsigned short)bf_rne(W1[idx]);
    }
    if (tid < BLK_N) {
        const int node = n0 + tid;
        sdeg[tid] = (node < N_NODES) ? deg[node] : 0;
    }
    // stage edge indices: 32 ints into bytes [0..128) of each asb row
#pragma unroll
    for (int t = 0; t < 2; ++t) {
        const int idx = t * 512 + tid;        // 0..1023 int4 slots
        const int r = idx >> 3, s4 = idx & 7;
        const int node = n0 + r;
        int4 v = make_int4(0, 0, 0, 0);
        if (node < N_NODES)
            v = *(const int4*)(csr + (size_t)node * CSR_STRIDE + s4 * 4);
        *(int4*)((char*)&asb[r][0] + s4 * 16) = v;
    }
    __syncthreads();

    // gather: group ty owns rows ty, ty+32, ty+64, ty+96; pairs (rA, rB=rA+32),
    // 16 row-loads in flight per group. Rows are fp8: one u32 per lane.
    for (int pp = 0; pp < 2; ++pp) {
        const int rA = ty + 64 * pp;
        const int rB = rA + 32;
        const int nodeA = n0 + rA;
        const int nodeB = n0 + rB;
        float aAx = 0.f, aAy = 0.f, aAz = 0.f, aAw = 0.f;
        float bAx = 0.f, bAy = 0.f, bAz = 0.f, bAw = 0.f;
        float aBx = 0.f, aBy = 0.f, aBz = 0.f, aBw = 0.f;
        float bBx = 0.f, bBy = 0.f, bBz = 0.f, bBw = 0.f;
        int nA = 0, nB = 0;
        if (nodeA < N_NODES) {
            nA = sdeg[rA]; nA = nA > CSR_STRIDE ? CSR_STRIDE : nA;
            const unsigned s = hin[(size_t)nodeA * 16 + sub];   // self term
            const f32x2 lo = __builtin_amdgcn_cvt_pk_f32_fp8((int)s, false);
            const f32x2 hi = __builtin_amdgcn_cvt_pk_f32_fp8((int)s, true);
            aAx = lo.x; aAy = lo.y; aAz = hi.x; aAw = hi.y;
        }
        if (nodeB < N_NODES) {
            nB = sdeg[rB]; nB = nB > CSR_STRIDE ? CSR_STRIDE : nB;
            const unsigned s = hin[(size_t)nodeB * 16 + sub];   // self term
            const f32x2 lo = __builtin_amdgcn_cvt_pk_f32_fp8((int)s, false);
            const f32x2 hi = __builtin_amdgcn_cvt_pk_f32_fp8((int)s, true);
            aBx = lo.x; aBy = lo.y; aBz = hi.x; aBw = hi.y;
        }
        const int nnA = nA > EMAX_LDS ? EMAX_LDS : nA;
        const int nnB = nB > EMAX_LDS ? EMAX_LDS : nB;
        const int* epA = (const int*)&asb[rA][0];
        const int* epB = (const int*)&asb[rB][0];
        const int mx = nnA > nnB ? nnA : nnB;
        for (int eb = 0; eb < mx; eb += 8) {
            unsigned rvA[8], rvB[8];
            const bool doA = eb < nnA;
            const bool doB = eb < nnB;
            if (doA) {
#pragma unroll
                for (int u = 0; u < 8; ++u) {
                    const int idx = eb + u;
                    const int cl = idx < nnA ? idx : nnA - 1;  // clamp: slots>=deg poison
                    rvA[u] = hin[(size_t)epA[cl] * 16 + sub];
                }
            }
            if (doB) {
#pragma unroll
                for (int u = 0; u < 8; ++u) {
                    const int idx = eb + u;
                    const int cl = idx < nnB ? idx : nnB - 1;
                    rvB[u] = hin[(size_t)epB[cl] * 16 + sub];
                }
            }
            if (doA) {
#pragma unroll
                for (int u = 0; u < 8; u += 2) {
                    if (eb + u < nnA) {
                        const f32x2 lo = __builtin_amdgcn_cvt_pk_f32_fp8((int)rvA[u], false);
                        const f32x2 hi = __builtin_amdgcn_cvt_pk_f32_fp8((int)rvA[u], true);
                        aAx += lo.x; aAy += lo.y; aAz += hi.x; aAw += hi.y;
                    }
                    if (eb + u + 1 < nnA) {
                        const f32x2 lo = __builtin_amdgcn_cvt_pk_f32_fp8((int)rvA[u + 1], false);
                        const f32x2 hi = __builtin_amdgcn_cvt_pk_f32_fp8((int)rvA[u + 1], true);
                        bAx += lo.x; bAy += lo.y; bAz += hi.x; bAw += hi.y;
                    }
                }
            }
            if (doB) {
#pragma unroll
                for (int u = 0; u < 8; u += 2) {
                    if (eb + u < nnB) {
                        const f32x2 lo = __builtin_amdgcn_cvt_pk_f32_fp8((int)rvB[u], false);
                        const f32x2 hi = __builtin_amdgcn_cvt_pk_f32_fp8((int)rvB[u], true);
                        aBx += lo.x; aBy += lo.y; aBz += hi.x; aBw += hi.y;
                    }
                    if (eb + u + 1 < nnB) {
                        const f32x2 lo = __builtin_amdgcn_cvt_pk_f32_fp8((int)rvB[u + 1], false);
                        const f32x2 hi = __builtin_amdgcn_cvt_pk_f32_fp8((int)rvB[u + 1], true);
                        bBx += lo.x; bBy += lo.y; bBz += hi.x; bBw += hi.y;
                    }
                }
            }
        }
        for (int t = EMAX_LDS; t < nA; ++t) { // rare tail (P~1e-4)
            const int s0 = csr[(size_t)nodeA * CSR_STRIDE + t];
            const unsigned a = hin[(size_t)s0 * 16 + sub];
            const f32x2 lo = __builtin_amdgcn_cvt_pk_f32_fp8((int)a, false);
            const f32x2 hi = __builtin_amdgcn_cvt_pk_f32_fp8((int)a, true);
            aAx += lo.x; aAy += lo.y; aAz += hi.x; aAw += hi.y;
        }
        for (int t = EMAX_LDS; t < nB; ++t) {
            const int s0 = csr[(size_t)nodeB * CSR_STRIDE + t];
            const unsigned a = hin[(size_t)s0 * 16 + sub];
            const f32x2 lo = __builtin_amdgcn_cvt_pk_f32_fp8((int)a, false);
            const f32x2 hi = __builtin_amdgcn_cvt_pk_f32_fp8((int)a, true);
            aBx += lo.x; aBy += lo.y; aBz += hi.x; aBw += hi.y;
        }
        // write agg rows bf16 (overwrites this row's eidx -- reads done)
        *(uint2*)((char*)&asb[rA][0] + sub * 8) = make_uint2(
            pack2(aAx + bAx, aAy + bAy), pack2(aAz + bAz, aAw + bAw));
        *(uint2*)((char*)&asb[rB][0] + sub * 8) = make_uint2(
            pack2(aBx + bBx, aBy + bBy), pack2(aBz + bBz, aBw + bBw));
    }
    __syncthreads();

    // ---- MFMA MLP ----
    const int wave = tid >> 6;            // row-block 0..7
    const int lane = tid & 63;
    const int lr = lane & 15;
    const int lg = lane >> 4;
    const f32x4 vzero = {0.f, 0.f, 0.f, 0.f};

    // GEMM1: z = relu(agg @ W1 + b1)
    f32x4 acc[4] = {vzero, vzero, vzero, vzero};
    {
        const char* ar = (const char*)&asb[wave * 16 + lr][0] + lg * 16;
        const bf16x8 a0 = *(const bf16x8*)ar;
        const bf16x8 a1 = *(const bf16x8*)(ar + 64);
#pragma unroll
        for (int cb = 0; cb < 4; ++cb) {
            const char* br = (const char*)&wsb[cb * 16 + lr][0] + lg * 16;
            const bf16x8 w0 = *(const bf16x8*)br;
            const bf16x8 w1 = *(const bf16x8*)(br + 64);
            acc[cb] = __builtin_amdgcn_mfma_f32_16x16x32_bf16(a0, w0, acc[cb], 0, 0, 0);
            acc[cb] = __builtin_amdgcn_mfma_f32_16x16x32_bf16(a1, w1, acc[cb], 0, 0, 0);
        }
    }
#pragma unroll
    for (int cb = 0; cb < 4; ++cb) {
        const float bias = b1[cb * 16 + lr];
#pragma unroll
        for (int rg = 0; rg < 4; ++rg) {
            const float v = fmaxf(acc[cb][rg] + bias, 0.f);
            asb[wave * 16 + lg * 4 + rg][cb * 16 + lr] = (unsigned short)bf_rne(v);
        }
    }
    __syncthreads();                       // all W1 B-frag reads done
#pragma unroll
    for (int t = 0; t < 8; ++t) {
        const int idx = t * 512 + tid;
        wsb[idx & 63][idx >> 6] = (unsigned short)bf_rne(W2[idx]);
    }
    __syncthreads();

    // GEMM2: h = relu(z @ W2 + b2)
#pragma unroll
    for (int cb = 0; cb < 4; ++cb) acc[cb] = vzero;
    {
        const char* ar = (const char*)&asb[wave * 16 + lr][0] + lg * 16;
        const bf16x8 a0 = *(const bf16x8*)ar;
        const bf16x8 a1 = *(const bf16x8*)(ar + 64);
#pragma unroll
        for (int cb = 0; cb < 4; ++cb) {
            const char* br = (const char*)&wsb[cb * 16 + lr][0] + lg * 16;
            const bf16x8 w0 = *(const bf16x8*)br;
            const bf16x8 w1 = *(const bf16x8*)(br + 64);
            acc[cb] = __builtin_amdgcn_mfma_f32_16x16x32_bf16(a0, w0, acc[cb], 0, 0, 0);
            acc[cb] = __builtin_amdgcn_mfma_f32_16x16x32_bf16(a1, w1, acc[cb], 0, 0, 0);
        }
    }
#pragma unroll
    for (int cb = 0; cb < 4; ++cb) {
        const float bias = b2[cb * 16 + lr];
#pragma unroll
        for (int rg = 0; rg < 4; ++rg) {
            const float v = fmaxf(acc[cb][rg] + bias, 0.f);
            asb[wave * 16 + lg * 4 + rg][cb * 16 + lr] = (unsigned short)bf_rne(v);
        }
    }
    __syncthreads();

    // coalesced copy-out: fp8 (intermediate layers) or bf16 (final layer)
#pragma unroll
    for (int t = 0; t < 4; ++t) {
        const int idx = t * 512 + tid;        // 0..2047
        const int m = idx >> 4, kv = idx & 15;
        if (n0 + m < N_NODES) {
            const uint2 v = *(const uint2*)((const char*)&asb[m][0] + kv * 8);
            if (FP8OUT) {
                hq_out[(size_t)(n0 + m) * 16 + kv] = pack_fp8x4(
                    bflo(v.x), bfhi(v.x), bflo(v.y), bfhi(v.y));
            } else {
                hbf_out[(size_t)(n0 + m) * 16 + kv] = v;
            }
        }
    }
}

// ---- fused pool+head: block per graph; wave 0 finishes post/ro/log_softmax
// in-register from the pooled row. Final h is bf16. ----
__global__ __launch_bounds__(256) void pool_head_kernel(
    const unsigned short* __restrict__ h, const int* __restrict__ batch,
    const float* __restrict__ Wp, const float* __restrict__ bp,
    const float* __restrict__ Wr, const float* __restrict__ br,
    float* __restrict__ out)
{
    const int graph = blockIdx.x;
    int l = 0, r = N_NODES;
    while (l < r) { int m = (l + r) >> 1; if (batch[m] < graph) l = m + 1; else r = m; }
    const int lo = l;
    r = N_NODES;
    while (l < r) { int m = (l + r) >> 1; if (batch[m] < graph + 1) l = m + 1; else r = m; }
    const int hi = l;

    const int lane = threadIdx.x & 63;
    const int wave = threadIdx.x >> 6;
    float acc = 0.0f;
    for (int i = lo + wave; i < hi; i += 4)
        acc += __uint_as_float(((unsigned)h[(size_t)i * N_HID + lane]) << 16);
    __shared__ float sacc[4][N_HID];
    sacc[wave][lane] = acc;
    __syncthreads();
    if (wave != 0) return;

    const float gv = sacc[0][lane] + sacc[1][lane] + sacc[2][lane] + sacc[3][lane];
    float acc2 = bp[lane];
#pragma unroll
    for (int k = 0; k < N_HID; ++k) {
        const float gk = __int_as_float(
            __builtin_amdgcn_readlane(__float_as_int(gv), k));
        acc2 = fmaf(gk, Wp[k * N_HID + lane], acc2);
    }
    const float y = fmaxf(acc2, 0.f);

    float logit = (lane < N_CLASS) ? br[lane] : 0.f;
#pragma unroll
    for (int k = 0; k < N_HID; ++k) {
        const float yk = __int_as_float(
            __builtin_amdgcn_readlane(__float_as_int(y), k));
        if (lane < N_CLASS)
            logit = fmaf(yk, Wr[k * N_CLASS + lane], logit);
    }

    __shared__ float slog[N_CLASS];
    if (lane < N_CLASS) slog[lane] = logit;
    if (lane < N_CLASS) {
        float m = -INFINITY;
#pragma unroll
        for (int c = 0; c < N_CLASS; ++c) m = fmaxf(m, slog[c]);
        float sum = 0.0f;
#pragma unroll
        for (int c = 0; c < N_CLASS; ++c) sum += expf(slog[c] - m);
        out[(size_t)graph * N_CLASS + lane] = logit - m - logf(sum);
    }
}

extern "C" void kernel_launch(void* const* d_in, const int* in_sizes, int n_in,
                              void* d_out, int out_size, void* d_ws, size_t ws_size,
                              hipStream_t stream)
{
    const float* x       = (const float*)d_in[0];
    const int*   ei      = (const int*)d_in[1];   // [2, E]: row0=src, row1=dst
    const int*   batch   = (const int*)d_in[2];
    const float* pre_w   = (const float*)d_in[3];
    const float* pre_b   = (const float*)d_in[4];
    const float* conv_w1 = (const float*)d_in[5];
    const float* conv_b1 = (const float*)d_in[6];
    const float* conv_w2 = (const float*)d_in[7];
    const float* conv_b2 = (const float*)d_in[8];
    const float* post_w  = (const float*)d_in[9];
    const float* post_b  = (const float*)d_in[10];
    const float* ro_w    = (const float*)d_in[11];
    const float* ro_b    = (const float*)d_in[12];
    float* out = (float*)d_out;

    // workspace layout (~51.6 MB)
    unsigned* hq0 = (unsigned*)d_ws;                    // 6.4 MB (fp8 h, 64B rows)
    unsigned* hq1 = hq0 + (size_t)N_NODES * 16;         // 6.4 MB
    uint2*    hbf = (uint2*)(hq1 + (size_t)N_NODES * 16); // 12.8 MB (bf16 final h)
    int*      deg = (int*)(hbf + (size_t)N_NODES * 16); // 400 KB
    int*      csr = deg + N_NODES;                      // 25.6 MB fixed-stride

    (void)hipMemsetAsync(deg, 0, N_NODES * sizeof(int), stream);

    pre_kernel<<<NTILES, 256, 0, stream>>>(x, pre_w, pre_b, hq0);
    hist_fill_kernel<<<HF_BLOCKS, 256, 0, stream>>>(ei, deg, csr);

    // 3 fused GIN layers: fp8 ping-pong hq0 -> hq1 -> hq0; final -> bf16 hbf
    gather_mlp_kernel<true><<<NT2, 512, 0, stream>>>(
        hq0, hq1, (uint2*)nullptr, csr, deg,
        conv_w1, conv_b1, conv_w2, conv_b2);
    gather_mlp_kernel<true><<<NT2, 512, 0, stream>>>(
        hq1, hq0, (uint2*)nullptr, csr, deg,
        conv_w1 + N_HID * N_HID, conv_b1 + N_HID,
        conv_w2 + N_HID * N_HID, conv_b2 + N_HID);
    gather_mlp_kernel<false><<<NT2, 512, 0, stream>>>(
        hq0, (unsigned*)nullptr, hbf, csr, deg,
        conv_w1 + 2 * N_HID * N_HID, conv_b1 + 2 * N_HID,
        conv_w2 + 2 * N_HID * N_HID, conv_b2 + 2 * N_HID);

    pool_head_kernel<<<N_GRAPHS, 256, 0, stream>>>(
        (const unsigned short*)hbf, batch, post_w, post_b, ro_w, ro_b, out);
}